// Round 7
// baseline (517.612 us; speedup 1.0000x reference)
//
#include <hip/hip_runtime.h>
#include <hip/hip_bf16.h>
#include <hip/hip_cooperative_groups.h>
#include <stdint.h>

namespace cg = cooperative_groups;

#define N_NODES 50000
#define N_EDGES 800000
#define TOT_EDGES (N_EDGES + N_NODES)
#define DIM 128
#define NEG 0.2f
#define BN_EPS 1e-5f
#define SKIPC 0.5f
#define NB 196          // buckets of 256 dst nodes
#define BCAP 6144       // per-bucket capacity (mean 4082, +31 sigma)
#define EPB 2048        // edges per binA block
#define BINA_BLKS ((N_EDGES + EPB - 1) / EPB)   // 391
#define GEMM_JOBS ((N_NODES + 63) >> 6)         // 782
#define ZN (NB + 512)

typedef __attribute__((ext_vector_type(8))) short short8;
typedef __attribute__((ext_vector_type(4))) float f32x4;

// ---------- helpers ----------
__device__ inline float bf2f(__hip_bfloat16 v) { return __bfloat162float(v); }
__device__ inline float u16f(unsigned short u) { return __uint_as_float(((unsigned int)u) << 16); }
__device__ inline unsigned short f2bu(float f) {
    __hip_bfloat16 b = __float2bfloat16(f);
    return *(unsigned short*)&b;
}
__device__ inline void fma8(float* acc, float ex, uint4 u) {
    acc[0] += ex * u16f((unsigned short)(u.x & 0xFFFFu));
    acc[1] += ex * u16f((unsigned short)(u.x >> 16));
    acc[2] += ex * u16f((unsigned short)(u.y & 0xFFFFu));
    acc[3] += ex * u16f((unsigned short)(u.y >> 16));
    acc[4] += ex * u16f((unsigned short)(u.z & 0xFFFFu));
    acc[5] += ex * u16f((unsigned short)(u.z >> 16));
    acc[6] += ex * u16f((unsigned short)(u.w & 0xFFFFu));
    acc[7] += ex * u16f((unsigned short)(u.w >> 16));
}
__device__ inline unsigned int pk2(float a, float b) {
    return (unsigned int)f2bu(a) | ((unsigned int)f2bu(b) << 16);
}

// ---------- fallback (ws too small) ----------
__global__ void zero_out_k(unsigned short* out, int n) {
    int g = blockIdx.x * 256 + threadIdx.x;
    if (g < n) out[g] = 0;
}

// ---------- CSR build phase A (bucketed scatter; self-detects int64/int32) ----------
__device__ inline void binA_body(int bid, const int* __restrict__ ei,
                                 int* __restrict__ bcnt,
                                 unsigned int* __restrict__ pairs) {
    __shared__ int cnt[NB], base[NB], cur[NB];
    __shared__ int sf;
    int t = threadIdx.x;
    if (t == 0) sf = 0;
    for (int i = t; i < NB; i += 256) cnt[i] = 0;
    __syncthreads();
    if (t < 16 && ei[2 * t + 1] != 0) atomicOr(&sf, 1);
    __syncthreads();
    int f = (sf == 0);   // 1 => int64
    int b0 = bid * EPB;
    unsigned int pk[8];
    int bk[8];
    #pragma unroll
    for (int j = 0; j < 8; ++j) bk[j] = -1;

    auto handle = [&](int slot, int s, int d) {
        if ((unsigned)d < N_NODES && (unsigned)s < N_NODES) {
            bk[slot] = d >> 8;
            pk[slot] = (unsigned int)s | ((unsigned int)(d & 255) << 16);
            atomicAdd(&cnt[bk[slot]], 1);
        }
    };

    if (f) {
        #pragma unroll
        for (int j = 0; j < 4; ++j) {
            int i0 = b0 + j * 512 + 2 * t;
            if (i0 < N_EDGES) {
                int4 sv = *(const int4*)(ei + 2 * (size_t)i0);
                int4 dv = *(const int4*)(ei + 2 * ((size_t)N_EDGES + i0));
                handle(2 * j, sv.x, dv.x);
                if (i0 + 1 < N_EDGES) handle(2 * j + 1, sv.z, dv.z);
            }
        }
    } else {
        #pragma unroll
        for (int j = 0; j < 8; ++j) {
            int g = b0 + j * 256 + t;
            if (g < N_EDGES) handle(j, ei[g], ei[N_EDGES + g]);
        }
    }
    __syncthreads();
    if (t < NB) {
        int c = cnt[t];
        base[t] = c ? atomicAdd(&bcnt[t], c) : 0;
        cur[t] = 0;
    }
    __syncthreads();
    #pragma unroll
    for (int j = 0; j < 8; ++j) {
        if (bk[j] >= 0) {
            int off = base[bk[j]] + atomicAdd(&cur[bk[j]], 1);
            if (off < BCAP) pairs[(size_t)bk[j] * BCAP + off] = pk[j];
        }
    }
}

// ---------- weight/param convert + dtype detect ----------
struct PrepJobs { const void* src[13]; float* dst[13]; int n[13]; };
__device__ inline void wcvt_body(int bid,
                                 const void* __restrict__ W0,
                                 const void* __restrict__ W1,
                                 const void* __restrict__ W2,
                                 unsigned short* __restrict__ Wb0,
                                 unsigned short* __restrict__ Wb1,
                                 unsigned short* __restrict__ Wb2,
                                 const PrepJobs& jobs,
                                 int* __restrict__ fflag) {
    __shared__ int cs;
    int t = threadIdx.x;
    if (t == 0) cs = 0;
    __syncthreads();
    {
        unsigned int w = ((const unsigned int*)W0)[t];
        float v0 = u16f((unsigned short)(w & 0xFFFFu));
        float a = fabsf(v0);
        int sane = (a < 2.0f && (a > 1e-20f || v0 == 0.0f)) ? 1 : 0;
        atomicAdd(&cs, sane);
    }
    __syncthreads();
    int f = (cs >= 128) ? 1 : 0;
    if (bid == 0 && t == 0) fflag[0] = f;
    if (bid < 148) {
        int g = bid * 256 + t;
        const void* W; unsigned short* Wb; int idx;
        if (g < 16384)        { W = W0; Wb = Wb0; idx = g; }
        else if (g < 32768)   { W = W1; Wb = Wb1; idx = g - 16384; }
        else if (g < 37888)   { W = W2; Wb = Wb2; idx = g - 32768; }
        else return;
        if (f) Wb[idx] = ((const unsigned short*)W)[idx];
        else   Wb[idx] = f2bu(((const float*)W)[idx]);
    } else {
        int j = bid - 148;
        int n = jobs.n[j];
        const void* s = jobs.src[j];
        float* d = jobs.dst[j];
        for (int i = t; i < n; i += 256)
            d[i] = f ? bf2f(((const __hip_bfloat16*)s)[i]) : ((const float*)s)[i];
    }
}

// ---------- CSR build phase B ----------
__device__ inline void binB_body(int b, const int* __restrict__ bcnt,
                                 const unsigned int* __restrict__ pairs,
                                 int* __restrict__ row_ptr,
                                 int* __restrict__ ssrc) {
    __shared__ int cntL[256], scanL[256], curL[256];
    __shared__ int sred[256];
    int t = threadIdx.x;
    int n0 = b * 256;
    int nn = min(256, N_NODES - n0);
    int cnt_b = min(bcnt[b], BCAP);
    int contrib = 0;
    if (t < b) contrib = min(bcnt[t], BCAP) + min(256, N_NODES - t * 256);
    sred[t] = contrib;
    __syncthreads();
    #pragma unroll
    for (int off = 128; off > 0; off >>= 1) {
        if (t < off) sred[t] += sred[t + off];
        __syncthreads();
    }
    int gbase = sred[0];
    if (b == NB - 1 && t == 0) row_ptr[N_NODES] = gbase + cnt_b + nn;

    const unsigned int* P = pairs + (size_t)b * BCAP;
    cntL[t] = (t < nn) ? 1 : 0;
    __syncthreads();
    for (int i = t; i < cnt_b; i += 256)
        atomicAdd(&cntL[P[i] >> 16], 1);
    __syncthreads();
    int v = cntL[t];
    scanL[t] = v;
    __syncthreads();
    for (int off = 1; off < 256; off <<= 1) {
        int x = (t >= off) ? scanL[t - off] : 0;
        __syncthreads();
        scanL[t] += x;
        __syncthreads();
    }
    int excl = scanL[t] - v;
    if (t < nn) row_ptr[n0 + t] = gbase + excl;
    curL[t] = excl;
    __syncthreads();
    if (t < nn) {
        int pos = atomicAdd(&curL[t], 1);
        ssrc[gbase + pos] = n0 + t;
    }
    for (int i = t; i < cnt_b; i += 256) {
        unsigned int p = P[i];
        int pos = atomicAdd(&curL[p >> 16], 1);
        ssrc[gbase + pos] = (int)(p & 0xFFFFu);
    }
}

// ---------- extended-weight build ----------
__device__ inline void wext_body(int bid,
                                 unsigned short* __restrict__ Wb0,
                                 unsigned short* __restrict__ Wb1,
                                 unsigned short* __restrict__ Wb2,
                                 const float* __restrict__ pAs0, const float* __restrict__ pAd0,
                                 const float* __restrict__ pAs1, const float* __restrict__ pAd1,
                                 const float* __restrict__ pAs2, const float* __restrict__ pAd2) {
    int g = bid * 256 + threadIdx.x;
    if (g < 2048) {
        int layer = g >> 10;
        int gi = g & 1023;
        int rowq = gi >> 7;
        int k = gi & 127;
        int hh = rowq & 3, dir = rowq >> 2;
        unsigned short* Wb = layer ? Wb1 : Wb0;
        const float* p = layer ? (dir ? pAd1 : pAs1) : (dir ? pAd0 : pAs0);
        float v = 0.f;
        #pragma unroll
        for (int c = 0; c < 32; ++c)
            v += p[hh * 32 + c] * u16f(Wb[(size_t)(hh * 32 + c) * 128 + k]);
        Wb[(size_t)(128 + dir * 4 + hh) * 128 + k] = f2bu(v);
    } else if (g < 2304) {
        int gi = g - 2048;
        int dir = gi >> 7;
        int k = gi & 127;
        const float* p = dir ? pAd2 : pAs2;
        float v = 0.f;
        #pragma unroll
        for (int c = 0; c < 40; ++c)
            v += p[c] * u16f(Wb2[(size_t)c * 128 + k]);
        Wb2[(size_t)(40 + dir) * 128 + k] = f2bu(v);
    }
}

// ---------- GEMM phase: grid-stride over 64-row jobs ----------
// AMODE 0: external X f32   AMODE 1: external X bf16
// AMODE 2: A = relu(X*scA+shA)   AMODE 3: A = relu(X*scA+shA + 0.5*relu(Xp*scB+shB))
template<int MT, int MV, int ALBASE, int NH, int AMODE>
__device__ inline void gemm_phase(int bid, int nblk,
                                  const void* __restrict__ X,
                                  const unsigned short* __restrict__ Xprev,
                                  const unsigned short* __restrict__ Wb,
                                  unsigned short* __restrict__ Y,
                                  float* __restrict__ als, float* __restrict__ ald, int n,
                                  const float* __restrict__ bnA, const float* __restrict__ gA,
                                  const float* __restrict__ beA,
                                  const float* __restrict__ bnB, const float* __restrict__ gB,
                                  const float* __restrict__ beB) {
    const int MROWS = ALBASE + 2 * NH;
    __shared__ float sAsc[128], sAsh[128], sBsc[128], sBsh[128];
    if (AMODE >= 2) {
        int t = threadIdx.x;
        const float invN = 1.f / (float)N_NODES;
        if (t < 128) {
            float mean = bnA[t] * invN;
            float var = fmaxf(bnA[128 + t] * invN - mean * mean, 0.f);
            float s = rsqrtf(var + BN_EPS) * gA[t];
            sAsc[t] = s;
            sAsh[t] = beA[t] - mean * s;
        } else if (AMODE == 3) {
            int c = t - 128;
            float mean = bnB[c] * invN;
            float var = fmaxf(bnB[128 + c] * invN - mean * mean, 0.f);
            float s = rsqrtf(var + BN_EPS) * gB[c];
            sBsc[c] = s;
            sBsh[c] = beB[c] - mean * s;
        }
        __syncthreads();
    }
    int lane = threadIdx.x & 63;
    int m = lane & 15, quad = lane >> 4;
    int wl = threadIdx.x >> 6;
    const int JOBS = (n + 63) >> 6;
    for (int job = bid; job < JOBS; job += nblk) {
        int r0 = (job << 6) + (wl << 4);
        if (r0 >= n) continue;
        f32x4 acc[MT];
        #pragma unroll
        for (int t = 0; t < MT; ++t) acc[t] = (f32x4){0.f, 0.f, 0.f, 0.f};
        int arow = min(r0 + m, n - 1);

        #pragma unroll
        for (int kc = 0; kc < 4; ++kc) {
            int k0 = kc * 32 + quad * 8;
            short8 a;
            if (AMODE == 0) {
                const float* xp = (const float*)X + (size_t)arow * 128 + k0;
                float4 x0 = *(const float4*)xp;
                float4 x1 = *(const float4*)(xp + 4);
                a[0] = (short)f2bu(x0.x); a[1] = (short)f2bu(x0.y);
                a[2] = (short)f2bu(x0.z); a[3] = (short)f2bu(x0.w);
                a[4] = (short)f2bu(x1.x); a[5] = (short)f2bu(x1.y);
                a[6] = (short)f2bu(x1.z); a[7] = (short)f2bu(x1.w);
            } else if (AMODE == 1) {
                a = *(const short8*)((const unsigned short*)X + (size_t)arow * 128 + k0);
            } else if (AMODE == 2) {
                short8 hv = *(const short8*)((const unsigned short*)X + (size_t)arow * 128 + k0);
                #pragma unroll
                for (int j = 0; j < 8; ++j) {
                    float v = u16f((unsigned short)hv[j]) * sAsc[k0 + j] + sAsh[k0 + j];
                    a[j] = (short)f2bu(fmaxf(v, 0.f));
                }
            } else {
                short8 hv = *(const short8*)((const unsigned short*)X + (size_t)arow * 128 + k0);
                short8 pv = *(const short8*)(Xprev + (size_t)arow * 128 + k0);
                #pragma unroll
                for (int j = 0; j < 8; ++j) {
                    float v0 = fmaxf(u16f((unsigned short)pv[j]) * sBsc[k0 + j] + sBsh[k0 + j], 0.f);
                    float v = u16f((unsigned short)hv[j]) * sAsc[k0 + j] + sAsh[k0 + j] + SKIPC * v0;
                    a[j] = (short)f2bu(fmaxf(v, 0.f));
                }
            }
            #pragma unroll
            for (int t = 0; t < MT; ++t) {
                int col = t * 16 + m;
                short8 b;
                if (col < MROWS) b = *(const short8*)(Wb + (size_t)col * 128 + k0);
                else             b = (short8){0,0,0,0,0,0,0,0};
                acc[t] = __builtin_amdgcn_mfma_f32_16x16x32_bf16(a, b, acc[t], 0, 0, 0);
            }
        }

        #pragma unroll
        for (int t = 0; t < MT; ++t) {
            int col = t * 16 + m;
            #pragma unroll
            for (int r = 0; r < 4; ++r) {
                int row = r0 + quad * 4 + r;
                if (row >= n) continue;
                if (col < MV) {
                    Y[(size_t)row * MV + col] = f2bu(acc[t][r]);
                } else if (col < ALBASE + NH) {
                    als[row * NH + (col - ALBASE)] = acc[t][r];
                } else if (col < ALBASE + 2 * NH) {
                    ald[row * NH + (col - ALBASE - NH)] = acc[t][r];
                }
            }
        }
    }
}

// ---------- BatchNorm stats body (bf16 input, short8 loads) ----------
__device__ inline void bn_stats_body(int vbid, int vgrid,
                                     const unsigned short* __restrict__ x,
                                     float* __restrict__ sum,
                                     float* __restrict__ sumsq, int n) {
    __shared__ float ss[128], sq[128];
    int t = threadIdx.x;
    int rt = t >> 4;
    int c8 = (t & 15) * 8;
    float s[8], q[8];
    #pragma unroll
    for (int j = 0; j < 8; ++j) { s[j] = 0.f; q[j] = 0.f; }
    for (int r = vbid * 16 + rt; r < n; r += vgrid * 16) {
        short8 v = *(const short8*)(x + (size_t)r * 128 + c8);
        #pragma unroll
        for (int j = 0; j < 8; ++j) {
            float f = u16f((unsigned short)v[j]);
            s[j] += f; q[j] += f * f;
        }
    }
    if (t < 128) { ss[t] = 0.f; sq[t] = 0.f; }
    __syncthreads();
    #pragma unroll
    for (int j = 0; j < 8; ++j) {
        atomicAdd(&ss[c8 + j], s[j]);
        atomicAdd(&sq[c8 + j], q[j]);
    }
    __syncthreads();
    if (t < 128) {
        atomicAdd(&sum[t], ss[t]);
        atomicAdd(&sumsq[t], sq[t]);
    }
}

// ================= cooperative mega kernels =================
struct M1Args {
    const int* ei; int* bcnt; unsigned int* pairs;
    const void* W0; const void* W1; const void* W2;
    unsigned short* Wb0; unsigned short* Wb1; unsigned short* Wb2;
    PrepJobs jobs; int* fflag;
    int* zreg;
    int* row_ptr; int* ssrc;
    const float* pAs0; const float* pAd0; const float* pAs1; const float* pAd1;
    const float* pAs2; const float* pAd2;
    const void* X; unsigned short* Y; float* als; float* ald; int n;
};

__global__ __launch_bounds__(256) void mega1_k(M1Args a) {
    cg::grid_group grid = cg::this_grid();
    int bid = blockIdx.x, nblk = gridDim.x;
    // P0: zero bcnt + bn buffers
    for (int i = bid * 256 + threadIdx.x; i < ZN; i += nblk * 256) a.zreg[i] = 0;
    grid.sync();
    // P1: binA + wcvt
    for (int job = bid; job < BINA_BLKS + 161; job += nblk) {
        if (job < BINA_BLKS) binA_body(job, a.ei, a.bcnt, a.pairs);
        else wcvt_body(job - BINA_BLKS, a.W0, a.W1, a.W2, a.Wb0, a.Wb1, a.Wb2, a.jobs, a.fflag);
    }
    grid.sync();
    // P2: binB + wext
    for (int job = bid; job < NB + 9; job += nblk) {
        if (job < NB) binB_body(job, a.bcnt, a.pairs, a.row_ptr, a.ssrc);
        else wext_body(job - NB, a.Wb0, a.Wb1, a.Wb2, a.pAs0, a.pAd0, a.pAs1, a.pAd1, a.pAs2, a.pAd2);
    }
    grid.sync();
    // P3: layer-0 GEMM
    int f = a.fflag[0];
    if (f) gemm_phase<9, 128, 128, 4, 1>(bid, nblk, a.X, nullptr, a.Wb0, a.Y, a.als, a.ald, a.n,
                                         nullptr, nullptr, nullptr, nullptr, nullptr, nullptr);
    else   gemm_phase<9, 128, 128, 4, 0>(bid, nblk, a.X, nullptr, a.Wb0, a.Y, a.als, a.ald, a.n,
                                         nullptr, nullptr, nullptr, nullptr, nullptr, nullptr);
}

struct M2Args {
    const unsigned short* Xs; float* sum; float* sumsq;
    const unsigned short* X; const unsigned short* Wb; unsigned short* Y;
    float* als; float* ald; int n;
    const float* bn; const float* g; const float* be;
};

__global__ __launch_bounds__(256) void mega2_k(M2Args a) {
    cg::grid_group grid = cg::this_grid();
    if (blockIdx.x < 256) bn_stats_body(blockIdx.x, 256, a.Xs, a.sum, a.sumsq, a.n);
    grid.sync();
    gemm_phase<9, 128, 128, 4, 2>(blockIdx.x, gridDim.x, a.X, nullptr, a.Wb, a.Y, a.als, a.ald, a.n,
                                  a.bn, a.g, a.be, nullptr, nullptr, nullptr);
}

struct M3Args {
    const unsigned short* Xs; float* sum; float* sumsq;
    const unsigned short* X; const unsigned short* Xprev; const unsigned short* Wb;
    unsigned short* Y; float* als; float* ald; int n;
    const float* bnA; const float* gA; const float* beA;
    const float* bnB; const float* gB; const float* beB;
};

__global__ __launch_bounds__(256) void mega3_k(M3Args a) {
    cg::grid_group grid = cg::this_grid();
    if (blockIdx.x < 256) bn_stats_body(blockIdx.x, 256, a.Xs, a.sum, a.sumsq, a.n);
    grid.sync();
    gemm_phase<3, 40, 40, 1, 3>(blockIdx.x, gridDim.x, a.X, a.Xprev, a.Wb, a.Y, a.als, a.ald, a.n,
                                a.bnA, a.gA, a.beA, a.bnB, a.gB, a.beB);
}

// ================= fallback standalone kernels =================
__global__ __launch_bounds__(256) void fat1_k(const int* __restrict__ ei,
                                              int* __restrict__ bcnt,
                                              unsigned int* __restrict__ pairs,
                                              const void* __restrict__ W0,
                                              const void* __restrict__ W1,
                                              const void* __restrict__ W2,
                                              unsigned short* __restrict__ Wb0,
                                              unsigned short* __restrict__ Wb1,
                                              unsigned short* __restrict__ Wb2,
                                              PrepJobs jobs,
                                              int* __restrict__ fflag) {
    if (blockIdx.x < BINA_BLKS) binA_body(blockIdx.x, ei, bcnt, pairs);
    else wcvt_body(blockIdx.x - BINA_BLKS, W0, W1, W2, Wb0, Wb1, Wb2, jobs, fflag);
}

__global__ __launch_bounds__(256) void fat2_k(const int* __restrict__ bcnt,
                                              const unsigned int* __restrict__ pairs,
                                              int* __restrict__ row_ptr,
                                              int* __restrict__ ssrc,
                                              unsigned short* __restrict__ Wb0,
                                              unsigned short* __restrict__ Wb1,
                                              unsigned short* __restrict__ Wb2,
                                              const float* __restrict__ pAs0, const float* __restrict__ pAd0,
                                              const float* __restrict__ pAs1, const float* __restrict__ pAd1,
                                              const float* __restrict__ pAs2, const float* __restrict__ pAd2) {
    if (blockIdx.x < NB) binB_body(blockIdx.x, bcnt, pairs, row_ptr, ssrc);
    else wext_body(blockIdx.x - NB, Wb0, Wb1, Wb2, pAs0, pAd0, pAs1, pAd1, pAs2, pAd2);
}

__global__ __launch_bounds__(256) void mfma_x_k(const void* __restrict__ X,
                                                const unsigned short* __restrict__ Wb,
                                                unsigned short* __restrict__ Y,
                                                float* __restrict__ als, float* __restrict__ ald,
                                                int n, const int* __restrict__ fflag) {
    if (fflag[0]) gemm_phase<9, 128, 128, 4, 1>(blockIdx.x, gridDim.x, X, nullptr, Wb, Y, als, ald, n,
                                                nullptr, nullptr, nullptr, nullptr, nullptr, nullptr);
    else          gemm_phase<9, 128, 128, 4, 0>(blockIdx.x, gridDim.x, X, nullptr, Wb, Y, als, ald, n,
                                                nullptr, nullptr, nullptr, nullptr, nullptr, nullptr);
}

__global__ __launch_bounds__(256) void mfma_aff_k(const unsigned short* __restrict__ X,
                                                  const unsigned short* __restrict__ Wb,
                                                  unsigned short* __restrict__ Y,
                                                  float* __restrict__ als, float* __restrict__ ald,
                                                  int n,
                                                  const float* __restrict__ bn,
                                                  const float* __restrict__ g,
                                                  const float* __restrict__ be) {
    gemm_phase<9, 128, 128, 4, 2>(blockIdx.x, gridDim.x, X, nullptr, Wb, Y, als, ald, n,
                                  bn, g, be, nullptr, nullptr, nullptr);
}

__global__ __launch_bounds__(256) void mfma_affskip_k(const unsigned short* __restrict__ X,
                                                      const unsigned short* __restrict__ Xprev,
                                                      const unsigned short* __restrict__ Wb,
                                                      unsigned short* __restrict__ Y,
                                                      float* __restrict__ als, float* __restrict__ ald,
                                                      int n,
                                                      const float* __restrict__ bnA,
                                                      const float* __restrict__ gA,
                                                      const float* __restrict__ beA,
                                                      const float* __restrict__ bnB,
                                                      const float* __restrict__ gB,
                                                      const float* __restrict__ beB) {
    gemm_phase<3, 40, 40, 1, 3>(blockIdx.x, gridDim.x, X, Xprev, Wb, Y, als, ald, n,
                                bnA, gA, beA, bnB, gB, beB);
}

__global__ __launch_bounds__(256) void bn_stats_k(const unsigned short* __restrict__ x,
                                                  float* __restrict__ sum,
                                                  float* __restrict__ sumsq, int n) {
    bn_stats_body(blockIdx.x, gridDim.x, x, sum, sumsq, n);
}

// ---------- GAT aggregation: 3-deep pipelined gather, bf16 output ----------
template<int H, int C, int LPG, int CPL, bool FINAL>
__global__ __launch_bounds__(256) void agg4_k(const unsigned short* __restrict__ hbuf,
                                              const float* __restrict__ als,
                                              const float* __restrict__ ald,
                                              const float* __restrict__ bias,
                                              const int* __restrict__ row_ptr,
                                              const int* __restrict__ ssrc,
                                              void* __restrict__ out,
                                              const int* __restrict__ fflag, int n) {
    const int HC = H * C;
    const int G = 64 / LPG;
    const int NV = CPL / 8;
    int gw = (blockIdx.x * blockDim.x + threadIdx.x) >> 6;
    if (gw >= n) return;
    int lane = threadIdx.x & 63;
    int grp = lane / LPG;
    int sl  = lane % LPG;
    int c0 = sl * CPL;
    bool act = c0 < HC;
    int hl = act ? (c0 / C) : 0;
    int d = gw;
    int beg = row_ptr[d], end = row_ptr[d + 1];
    float adh = ald[d * H + hl];

    float denom = 0.f;
    float acc[CPL];
    #pragma unroll
    for (int j = 0; j < CPL; ++j) acc[j] = 0.f;

    int i0 = beg + grp;
    bool h0 = i0 < end;
    bool h1 = (i0 + G) < end;
    bool h2 = (i0 + 2 * G) < end;
    float al0 = 0.f, al1 = 0.f, al2 = 0.f;
    uint4 u0[NV], u1[NV], u2[NV];
    if (h0) {
        int s = ssrc[i0];
        al0 = als[s * H + hl];
        if (act) {
            const uint4* hp = (const uint4*)(hbuf + (size_t)s * HC + c0);
            #pragma unroll
            for (int v = 0; v < NV; ++v) u0[v] = hp[v];
        }
    }
    if (h1) {
        int s = ssrc[i0 + G];
        al1 = als[s * H + hl];
        if (act) {
            const uint4* hp = (const uint4*)(hbuf + (size_t)s * HC + c0);
            #pragma unroll
            for (int v = 0; v < NV; ++v) u1[v] = hp[v];
        }
    }
    if (h2) {
        int s = ssrc[i0 + 2 * G];
        al2 = als[s * H + hl];
        if (act) {
            const uint4* hp = (const uint4*)(hbuf + (size_t)s * HC + c0);
            #pragma unroll
            for (int v = 0; v < NV; ++v) u2[v] = hp[v];
        }
    }
    int inext = i0 + 3 * G;

    while (h0) {
        bool h3 = inext < end;
        float al3 = 0.f;
        uint4 u3[NV];
        if (h3) {
            int s = ssrc[inext];
            al3 = als[s * H + hl];
            if (act) {
                const uint4* hp = (const uint4*)(hbuf + (size_t)s * HC + c0);
                #pragma unroll
                for (int v = 0; v < NV; ++v) u3[v] = hp[v];
            }
        }
        float t = al0 + adh;
        t = t > 0.f ? t : NEG * t;
        float ex = __expf(t);
        denom += ex;
        if (act) {
            #pragma unroll
            for (int v = 0; v < NV; ++v) fma8(acc + v * 8, ex, u0[v]);
        }
        h0 = h1; al0 = al1;
        #pragma unroll
        for (int v = 0; v < NV; ++v) u0[v] = u1[v];
        h1 = h2; al1 = al2;
        #pragma unroll
        for (int v = 0; v < NV; ++v) u1[v] = u2[v];
        h2 = h3; al2 = al3;
        #pragma unroll
        for (int v = 0; v < NV; ++v) u2[v] = u3[v];
        inext += G;
    }

    #pragma unroll
    for (int off = LPG; off < 64; off <<= 1) {
        denom += __shfl_xor(denom, off, 64);
        #pragma unroll
        for (int j = 0; j < CPL; ++j) acc[j] += __shfl_xor(acc[j], off, 64);
    }

    if (grp == 0 && act) {
        float inv = 1.f / denom;
        float vals[CPL];
        #pragma unroll
        for (int j = 0; j < CPL; ++j) vals[j] = acc[j] * inv + bias[c0 + j];
        if (FINAL && !fflag[0]) {
            float* of = (float*)out + (size_t)d * HC + c0;
            #pragma unroll
            for (int j = 0; j < CPL; ++j) of[j] = vals[j];
        } else {
            unsigned short* ob = (unsigned short*)out + (size_t)d * HC + c0;
            #pragma unroll
            for (int v = 0; v < NV; ++v) {
                uint4 pk;
                pk.x = pk2(vals[v * 8 + 0], vals[v * 8 + 1]);
                pk.y = pk2(vals[v * 8 + 2], vals[v * 8 + 3]);
                pk.z = pk2(vals[v * 8 + 4], vals[v * 8 + 5]);
                pk.w = pk2(vals[v * 8 + 6], vals[v * 8 + 7]);
                *(uint4*)(ob + v * 8) = pk;
            }
        }
    }
}

// ---------- launch ----------
extern "C" void kernel_launch(void* const* d_in, const int* in_sizes, int n_in,
                              void* d_out, int out_size, void* d_ws, size_t ws_size,
                              hipStream_t stream) {
    const void* x   = d_in[0];
    const void* W0  = d_in[1];
    const void* as0 = d_in[2];
    const void* ad0 = d_in[3];
    const void* b0  = d_in[4];
    const void* g0  = d_in[5];
    const void* be0 = d_in[6];
    const void* W1  = d_in[7];
    const void* as1 = d_in[8];
    const void* ad1 = d_in[9];
    const void* b1  = d_in[10];
    const void* g1  = d_in[11];
    const void* be1 = d_in[12];
    const void* W2  = d_in[13];
    const void* as2 = d_in[14];
    const void* ad2 = d_in[15];
    const void* b2  = d_in[16];
    const int* ei = (const int*)d_in[17];

    char* w = (char*)d_ws;
    size_t off = 0;
    auto alloc = [&](size_t bytes) -> void* {
        void* p = w + off;
        off = (off + bytes + 255) & ~(size_t)255;
        return p;
    };
    unsigned short* hbf = (unsigned short*)alloc((size_t)N_NODES * 128 * 2);
    unsigned short* hA0 = (unsigned short*)alloc((size_t)N_NODES * 128 * 2);
    unsigned short* hA1 = (unsigned short*)alloc((size_t)N_NODES * 128 * 2);
    float* als = (float*)alloc((size_t)N_NODES * 4 * 4);
    float* ald = (float*)alloc((size_t)N_NODES * 4 * 4);
    unsigned short* Wb0 = (unsigned short*)alloc((size_t)136 * 128 * 2);
    unsigned short* Wb1 = (unsigned short*)alloc((size_t)136 * 128 * 2);
    unsigned short* Wb2 = (unsigned short*)alloc((size_t)42 * 128 * 2);
    float* prm = (float*)alloc(2048 * 4);
    int* zreg = (int*)alloc((size_t)ZN * 4);
    int* bcnt = zreg;
    float* bn0 = (float*)(zreg + NB);
    float* bn1 = bn0 + 256;
    int* row_ptr = (int*)alloc((size_t)(N_NODES + 1) * 4);
    int* ssrc    = (int*)alloc((size_t)TOT_EDGES * 4);
    unsigned int* pairs = (unsigned int*)alloc((size_t)NB * BCAP * 4);
    int* fflag   = (int*)alloc(256);

    float* pAs0 = prm + 0,   * pAd0 = prm + 128,  * pB0 = prm + 256;
    float* pG0  = prm + 384, * pBe0 = prm + 512;
    float* pAs1 = prm + 640, * pAd1 = prm + 768,  * pB1 = prm + 896;
    float* pG1  = prm + 1024,* pBe1 = prm + 1152;
    float* pAs2 = prm + 1280,* pAd2 = prm + 1320, * pB2 = prm + 1360;

    if (off > ws_size) {
        zero_out_k<<<(out_size + 255) / 256, 256, 0, stream>>>((unsigned short*)d_out, out_size);
        return;
    }

    const int MB = GEMM_JOBS;
    const int AB = (N_NODES * 64 + 255) / 256;

    PrepJobs jobs;
    const void* srcs[13] = { as0, ad0, b0, g0, be0, as1, ad1, b1, g1, be1, as2, ad2, b2 };
    float* dsts[13] = { pAs0, pAd0, pB0, pG0, pBe0, pAs1, pAd1, pB1, pG1, pBe1, pAs2, pAd2, pB2 };
    int ns[13] = { 128,128,128,128,128, 128,128,128,128,128, 40,40,40 };
    for (int i = 0; i < 13; ++i) { jobs.src[i] = srcs[i]; jobs.dst[i] = dsts[i]; jobs.n[i] = ns[i]; }

    // occupancy + CU count (cached; host-only queries, graph-safe)
    static int s_init = 0, s_cu = 0, s_o1 = 0, s_o2 = 0, s_o3 = 0;
    static int s_coop = -1;   // -1 unknown, 0 failed once -> always fallback, 1 working
    if (!s_init) {
        hipDeviceProp_t prop;
        if (hipGetDeviceProperties(&prop, 0) == hipSuccess) s_cu = prop.multiProcessorCount;
        (void)hipOccupancyMaxActiveBlocksPerMultiprocessor(&s_o1, mega1_k, 256, 0);
        (void)hipOccupancyMaxActiveBlocksPerMultiprocessor(&s_o2, mega2_k, 256, 0);
        (void)hipOccupancyMaxActiveBlocksPerMultiprocessor(&s_o3, mega3_k, 256, 0);
        s_init = 1;
    }
    bool tryCoop = (s_coop != 0) && s_cu > 0 && s_o1 > 0 && s_o2 > 0 && s_o3 > 0;

    // ---- stage 1: prep + layer-0 GEMM ----
    bool done = false;
    if (tryCoop) {
        M1Args a1;
        a1.ei = ei; a1.bcnt = bcnt; a1.pairs = pairs;
        a1.W0 = W0; a1.W1 = W1; a1.W2 = W2;
        a1.Wb0 = Wb0; a1.Wb1 = Wb1; a1.Wb2 = Wb2;
        a1.jobs = jobs; a1.fflag = fflag;
        a1.zreg = zreg;
        a1.row_ptr = row_ptr; a1.ssrc = ssrc;
        a1.pAs0 = pAs0; a1.pAd0 = pAd0; a1.pAs1 = pAs1; a1.pAd1 = pAd1;
        a1.pAs2 = pAs2; a1.pAd2 = pAd2;
        a1.X = x; a1.Y = hbf; a1.als = als; a1.ald = ald; a1.n = N_NODES;
        void* p1[] = { (void*)&a1 };
        int g1 = s_cu * s_o1; if (g1 > GEMM_JOBS) g1 = GEMM_JOBS;
        if (hipLaunchCooperativeKernel((const void*)mega1_k, dim3(g1), dim3(256), p1, 0, stream) == hipSuccess)
            done = true;
        else { (void)hipGetLastError(); s_coop = 0; tryCoop = false; }
    }
    if (!done) {
        hipMemsetAsync(zreg, 0, (size_t)ZN * 4, stream);
        fat1_k<<<BINA_BLKS + 161, 256, 0, stream>>>(ei, bcnt, pairs, W0, W1, W2, Wb0, Wb1, Wb2, jobs, fflag);
        fat2_k<<<NB + 9, 256, 0, stream>>>(bcnt, pairs, row_ptr, ssrc, Wb0, Wb1, Wb2,
                                           pAs0, pAd0, pAs1, pAd1, pAs2, pAd2);
        mfma_x_k<<<MB, 256, 0, stream>>>(x, Wb0, hbf, als, ald, N_NODES, fflag);
    }

    // ---- layer-0 aggregation ----
    agg4_k<4, 32, 8, 16, false><<<AB, 256, 0, stream>>>(hbf, als, ald, pB0, row_ptr, ssrc, hA0, fflag, N_NODES);

    // ---- stage 2: bn0 stats + layer-1 GEMM ----
    done = false;
    if (tryCoop) {
        M2Args a2;
        a2.Xs = hA0; a2.sum = bn0; a2.sumsq = bn0 + 128;
        a2.X = hA0; a2.Wb = Wb1; a2.Y = hbf;
        a2.als = als; a2.ald = ald; a2.n = N_NODES;
        a2.bn = bn0; a2.g = pG0; a2.be = pBe0;
        void* p2[] = { (void*)&a2 };
        int g2 = s_cu * s_o2; if (g2 > GEMM_JOBS) g2 = GEMM_JOBS;
        if (hipLaunchCooperativeKernel((const void*)mega2_k, dim3(g2), dim3(256), p2, 0, stream) == hipSuccess)
            done = true;
        else { (void)hipGetLastError(); s_coop = 0; tryCoop = false; }
    }
    if (!done) {
        bn_stats_k<<<256, 256, 0, stream>>>(hA0, bn0, bn0 + 128, N_NODES);
        mfma_aff_k<<<MB, 256, 0, stream>>>(hA0, Wb1, hbf, als, ald, N_NODES, bn0, pG0, pBe0);
    }

    // ---- layer-1 aggregation ----
    agg4_k<4, 32, 8, 16, false><<<AB, 256, 0, stream>>>(hbf, als, ald, pB1, row_ptr, ssrc, hA1, fflag, N_NODES);

    // ---- stage 3: bn1 stats + layer-2 GEMM ----
    done = false;
    if (tryCoop) {
        M3Args a3;
        a3.Xs = hA1; a3.sum = bn1; a3.sumsq = bn1 + 128;
        a3.X = hA1; a3.Xprev = hA0; a3.Wb = Wb2; a3.Y = hbf;
        a3.als = als; a3.ald = ald; a3.n = N_NODES;
        a3.bnA = bn1; a3.gA = pG1; a3.beA = pBe1;
        a3.bnB = bn0; a3.gB = pG0; a3.beB = pBe0;
        void* p3[] = { (void*)&a3 };
        int g3 = s_cu * s_o3; if (g3 > GEMM_JOBS) g3 = GEMM_JOBS;
        if (hipLaunchCooperativeKernel((const void*)mega3_k, dim3(g3), dim3(256), p3, 0, stream) == hipSuccess)
            done = true;
        else { (void)hipGetLastError(); s_coop = 0; }
    }
    if (!done) {
        bn_stats_k<<<256, 256, 0, stream>>>(hA1, bn1, bn1 + 128, N_NODES);
        mfma_affskip_k<<<MB, 256, 0, stream>>>(hA1, hA0, Wb2, hbf, als, ald, N_NODES,
                                               bn1, pG1, pBe1, bn0, pG0, pBe0);
    }
    if (s_coop == -1 && tryCoop) s_coop = 1;

    // ---- layer-2 aggregation -> output ----
    agg4_k<1, 40, 8, 8, true><<<AB, 256, 0, stream>>>(hbf, als, ald, pB2, row_ptr, ssrc, d_out, fflag, N_NODES);
}

// Round 8
// 312.201 us; speedup vs baseline: 1.6579x; 1.6579x over previous
//
#include <hip/hip_runtime.h>
#include <hip/hip_bf16.h>
#include <stdint.h>

#define N_NODES 50000
#define N_EDGES 800000
#define TOT_EDGES (N_EDGES + N_NODES)
#define DIM 128
#define NEG 0.2f
#define BN_EPS 1e-5f
#define SKIPC 0.5f
#define NB 196          // buckets of 256 dst nodes
#define BCAP 6144       // per-bucket capacity (mean 4082, +31 sigma)
#define EPB 2048        // edges per binA block
#define BINA_BLKS ((N_EDGES + EPB - 1) / EPB)   // 391
#define GEMM_JOBS ((N_NODES + 63) >> 6)         // 782
#define ZN (NB + 512)

typedef __attribute__((ext_vector_type(8))) short short8;
typedef __attribute__((ext_vector_type(4))) float f32x4;

// ---------- helpers ----------
__device__ inline float bf2f(__hip_bfloat16 v) { return __bfloat162float(v); }
__device__ inline float u16f(unsigned short u) { return __uint_as_float(((unsigned int)u) << 16); }
__device__ inline unsigned short f2bu(float f) {
    __hip_bfloat16 b = __float2bfloat16(f);
    return *(unsigned short*)&b;
}
__device__ inline void fma8(float* acc, float ex, uint4 u) {
    acc[0] += ex * u16f((unsigned short)(u.x & 0xFFFFu));
    acc[1] += ex * u16f((unsigned short)(u.x >> 16));
    acc[2] += ex * u16f((unsigned short)(u.y & 0xFFFFu));
    acc[3] += ex * u16f((unsigned short)(u.y >> 16));
    acc[4] += ex * u16f((unsigned short)(u.z & 0xFFFFu));
    acc[5] += ex * u16f((unsigned short)(u.z >> 16));
    acc[6] += ex * u16f((unsigned short)(u.w & 0xFFFFu));
    acc[7] += ex * u16f((unsigned short)(u.w >> 16));
}
__device__ inline unsigned int pk2(float a, float b) {
    return (unsigned int)f2bu(a) | ((unsigned int)f2bu(b) << 16);
}

// ---------- fallback (ws too small) ----------
__global__ void zero_out_k(unsigned short* out, int n) {
    int g = blockIdx.x * 256 + threadIdx.x;
    if (g < n) out[g] = 0;
}

// ---------- CSR build phase A (bucketed scatter; self-detects int64/int32) ----------
__device__ inline void binA_body(int bid, const int* __restrict__ ei,
                                 int* __restrict__ bcnt,
                                 unsigned int* __restrict__ pairs) {
    __shared__ int cnt[NB], base[NB], cur[NB];
    __shared__ int sf;
    int t = threadIdx.x;
    if (t == 0) sf = 0;
    for (int i = t; i < NB; i += 256) cnt[i] = 0;
    __syncthreads();
    if (t < 16 && ei[2 * t + 1] != 0) atomicOr(&sf, 1);
    __syncthreads();
    int f = (sf == 0);   // 1 => int64
    int b0 = bid * EPB;
    unsigned int pk[8];
    int bk[8];
    #pragma unroll
    for (int j = 0; j < 8; ++j) bk[j] = -1;

    auto handle = [&](int slot, int s, int d) {
        if ((unsigned)d < N_NODES && (unsigned)s < N_NODES) {
            bk[slot] = d >> 8;
            pk[slot] = (unsigned int)s | ((unsigned int)(d & 255) << 16);
            atomicAdd(&cnt[bk[slot]], 1);
        }
    };

    if (f) {
        #pragma unroll
        for (int j = 0; j < 4; ++j) {
            int i0 = b0 + j * 512 + 2 * t;
            if (i0 < N_EDGES) {
                int4 sv = *(const int4*)(ei + 2 * (size_t)i0);
                int4 dv = *(const int4*)(ei + 2 * ((size_t)N_EDGES + i0));
                handle(2 * j, sv.x, dv.x);
                if (i0 + 1 < N_EDGES) handle(2 * j + 1, sv.z, dv.z);
            }
        }
    } else {
        #pragma unroll
        for (int j = 0; j < 8; ++j) {
            int g = b0 + j * 256 + t;
            if (g < N_EDGES) handle(j, ei[g], ei[N_EDGES + g]);
        }
    }
    __syncthreads();
    if (t < NB) {
        int c = cnt[t];
        base[t] = c ? atomicAdd(&bcnt[t], c) : 0;
        cur[t] = 0;
    }
    __syncthreads();
    #pragma unroll
    for (int j = 0; j < 8; ++j) {
        if (bk[j] >= 0) {
            int off = base[bk[j]] + atomicAdd(&cur[bk[j]], 1);
            if (off < BCAP) pairs[(size_t)bk[j] * BCAP + off] = pk[j];
        }
    }
}

// ---------- weight/param convert + dtype detect ----------
struct PrepJobs { const void* src[13]; float* dst[13]; int n[13]; };
__device__ inline void wcvt_body(int bid,
                                 const void* __restrict__ W0,
                                 const void* __restrict__ W1,
                                 const void* __restrict__ W2,
                                 unsigned short* __restrict__ Wb0,
                                 unsigned short* __restrict__ Wb1,
                                 unsigned short* __restrict__ Wb2,
                                 const PrepJobs& jobs,
                                 int* __restrict__ fflag) {
    __shared__ int cs;
    int t = threadIdx.x;
    if (t == 0) cs = 0;
    __syncthreads();
    {
        unsigned int w = ((const unsigned int*)W0)[t];
        float v0 = u16f((unsigned short)(w & 0xFFFFu));
        float a = fabsf(v0);
        int sane = (a < 2.0f && (a > 1e-20f || v0 == 0.0f)) ? 1 : 0;
        atomicAdd(&cs, sane);
    }
    __syncthreads();
    int f = (cs >= 128) ? 1 : 0;
    if (bid == 0 && t == 0) fflag[0] = f;
    if (bid < 148) {
        int g = bid * 256 + t;
        const void* W; unsigned short* Wb; int idx;
        if (g < 16384)        { W = W0; Wb = Wb0; idx = g; }
        else if (g < 32768)   { W = W1; Wb = Wb1; idx = g - 16384; }
        else if (g < 37888)   { W = W2; Wb = Wb2; idx = g - 32768; }
        else return;
        if (f) Wb[idx] = ((const unsigned short*)W)[idx];
        else   Wb[idx] = f2bu(((const float*)W)[idx]);
    } else {
        int j = bid - 148;
        int n = jobs.n[j];
        const void* s = jobs.src[j];
        float* d = jobs.dst[j];
        for (int i = t; i < n; i += 256)
            d[i] = f ? bf2f(((const __hip_bfloat16*)s)[i]) : ((const float*)s)[i];
    }
}

// ---------- extended-weight build from RAW inputs (independent of wcvt) ----------
// Wext rows: layer 0/1 row 128+dir*4+hh = sum_c a[hh][c]*W[hh*32+c][:]
//            layer 2   row 40+dir       = sum_c a[c]*W2[c][:]
// Reads raw W*, as*, ad* (f32 or bf16, self-detected) -> no dependency on wcvt.
__device__ inline void wext_raw_body(int bid,
                                     const void* __restrict__ W0,
                                     const void* __restrict__ W1,
                                     const void* __restrict__ W2,
                                     const void* __restrict__ as0, const void* __restrict__ ad0,
                                     const void* __restrict__ as1, const void* __restrict__ ad1,
                                     const void* __restrict__ as2, const void* __restrict__ ad2,
                                     unsigned short* __restrict__ Wb0,
                                     unsigned short* __restrict__ Wb1,
                                     unsigned short* __restrict__ Wb2) {
    __shared__ int cs;
    int t = threadIdx.x;
    if (t == 0) cs = 0;
    __syncthreads();
    {
        unsigned int w = ((const unsigned int*)W0)[t];
        float v0 = u16f((unsigned short)(w & 0xFFFFu));
        float a = fabsf(v0);
        int sane = (a < 2.0f && (a > 1e-20f || v0 == 0.0f)) ? 1 : 0;
        atomicAdd(&cs, sane);
    }
    __syncthreads();
    int f = (cs >= 128) ? 1 : 0;
    auto rd = [&](const void* p, int idx) -> float {
        return f ? u16f(((const unsigned short*)p)[idx]) : ((const float*)p)[idx];
    };
    int g = bid * 256 + t;
    if (g < 2048) {
        int layer = g >> 10;
        int gi = g & 1023;
        int rowq = gi >> 7;
        int k = gi & 127;
        int hh = rowq & 3, dir = rowq >> 2;
        const void* W = layer ? W1 : W0;
        const void* p = layer ? (dir ? ad1 : as1) : (dir ? ad0 : as0);
        unsigned short* Wb = layer ? Wb1 : Wb0;
        float v = 0.f;
        #pragma unroll
        for (int c = 0; c < 32; ++c)
            v += rd(p, hh * 32 + c) * rd(W, (hh * 32 + c) * 128 + k);
        Wb[(size_t)(128 + dir * 4 + hh) * 128 + k] = f2bu(v);
    } else if (g < 2304) {
        int gi = g - 2048;
        int dir = gi >> 7;
        int k = gi & 127;
        const void* p = dir ? ad2 : as2;
        float v = 0.f;
        #pragma unroll
        for (int c = 0; c < 40; ++c)
            v += rd(p, c) * rd(W2, c * 128 + k);
        Wb2[(size_t)(40 + dir) * 128 + k] = f2bu(v);
    }
}

// ---------- CSR build phase B ----------
__device__ inline void binB_body(int b, const int* __restrict__ bcnt,
                                 const unsigned int* __restrict__ pairs,
                                 int* __restrict__ row_ptr,
                                 int* __restrict__ ssrc) {
    __shared__ int cntL[256], scanL[256], curL[256];
    __shared__ int sred[256];
    int t = threadIdx.x;
    int n0 = b * 256;
    int nn = min(256, N_NODES - n0);
    int cnt_b = min(bcnt[b], BCAP);
    int contrib = 0;
    if (t < b) contrib = min(bcnt[t], BCAP) + min(256, N_NODES - t * 256);
    sred[t] = contrib;
    __syncthreads();
    #pragma unroll
    for (int off = 128; off > 0; off >>= 1) {
        if (t < off) sred[t] += sred[t + off];
        __syncthreads();
    }
    int gbase = sred[0];
    if (b == NB - 1 && t == 0) row_ptr[N_NODES] = gbase + cnt_b + nn;

    const unsigned int* P = pairs + (size_t)b * BCAP;
    cntL[t] = (t < nn) ? 1 : 0;
    __syncthreads();
    for (int i = t; i < cnt_b; i += 256)
        atomicAdd(&cntL[P[i] >> 16], 1);
    __syncthreads();
    int v = cntL[t];
    scanL[t] = v;
    __syncthreads();
    for (int off = 1; off < 256; off <<= 1) {
        int x = (t >= off) ? scanL[t - off] : 0;
        __syncthreads();
        scanL[t] += x;
        __syncthreads();
    }
    int excl = scanL[t] - v;
    if (t < nn) row_ptr[n0 + t] = gbase + excl;
    curL[t] = excl;
    __syncthreads();
    if (t < nn) {
        int pos = atomicAdd(&curL[t], 1);
        ssrc[gbase + pos] = n0 + t;
    }
    for (int i = t; i < cnt_b; i += 256) {
        unsigned int p = P[i];
        int pos = atomicAdd(&curL[p >> 16], 1);
        ssrc[gbase + pos] = (int)(p & 0xFFFFu);
    }
}

// ---------- GEMM job body: one 64-row job per call ----------
// AMODE 0: external X f32   AMODE 1: external X bf16
// AMODE 2: A = relu(X*scA+shA)   AMODE 3: A = relu(X*scA+shA + 0.5*relu(Xp*scB+shB))
template<int MT, int MV, int ALBASE, int NH, int AMODE>
__device__ inline void gemm_job(int job,
                                const void* __restrict__ X,
                                const unsigned short* __restrict__ Xprev,
                                const unsigned short* __restrict__ Wb,
                                unsigned short* __restrict__ Y,
                                float* __restrict__ als, float* __restrict__ ald, int n,
                                const float* __restrict__ bnA, const float* __restrict__ gA,
                                const float* __restrict__ beA,
                                const float* __restrict__ bnB, const float* __restrict__ gB,
                                const float* __restrict__ beB) {
    const int MROWS = ALBASE + 2 * NH;
    __shared__ float sAsc[128], sAsh[128], sBsc[128], sBsh[128];
    if (AMODE >= 2) {
        int t = threadIdx.x;
        const float invN = 1.f / (float)N_NODES;
        if (t < 128) {
            float mean = bnA[t] * invN;
            float var = fmaxf(bnA[128 + t] * invN - mean * mean, 0.f);
            float s = rsqrtf(var + BN_EPS) * gA[t];
            sAsc[t] = s;
            sAsh[t] = beA[t] - mean * s;
        } else if (AMODE == 3) {
            int c = t - 128;
            float mean = bnB[c] * invN;
            float var = fmaxf(bnB[128 + c] * invN - mean * mean, 0.f);
            float s = rsqrtf(var + BN_EPS) * gB[c];
            sBsc[c] = s;
            sBsh[c] = beB[c] - mean * s;
        }
        __syncthreads();
    }
    int lane = threadIdx.x & 63;
    int m = lane & 15, quad = lane >> 4;
    int wl = threadIdx.x >> 6;
    int r0 = (job << 6) + (wl << 4);
    if (r0 >= n) return;
    f32x4 acc[MT];
    #pragma unroll
    for (int t = 0; t < MT; ++t) acc[t] = (f32x4){0.f, 0.f, 0.f, 0.f};
    int arow = min(r0 + m, n - 1);

    #pragma unroll
    for (int kc = 0; kc < 4; ++kc) {
        int k0 = kc * 32 + quad * 8;
        short8 a;
        if (AMODE == 0) {
            const float* xp = (const float*)X + (size_t)arow * 128 + k0;
            float4 x0 = *(const float4*)xp;
            float4 x1 = *(const float4*)(xp + 4);
            a[0] = (short)f2bu(x0.x); a[1] = (short)f2bu(x0.y);
            a[2] = (short)f2bu(x0.z); a[3] = (short)f2bu(x0.w);
            a[4] = (short)f2bu(x1.x); a[5] = (short)f2bu(x1.y);
            a[6] = (short)f2bu(x1.z); a[7] = (short)f2bu(x1.w);
        } else if (AMODE == 1) {
            a = *(const short8*)((const unsigned short*)X + (size_t)arow * 128 + k0);
        } else if (AMODE == 2) {
            short8 hv = *(const short8*)((const unsigned short*)X + (size_t)arow * 128 + k0);
            #pragma unroll
            for (int j = 0; j < 8; ++j) {
                float v = u16f((unsigned short)hv[j]) * sAsc[k0 + j] + sAsh[k0 + j];
                a[j] = (short)f2bu(fmaxf(v, 0.f));
            }
        } else {
            short8 hv = *(const short8*)((const unsigned short*)X + (size_t)arow * 128 + k0);
            short8 pv = *(const short8*)(Xprev + (size_t)arow * 128 + k0);
            #pragma unroll
            for (int j = 0; j < 8; ++j) {
                float v0 = fmaxf(u16f((unsigned short)pv[j]) * sBsc[k0 + j] + sBsh[k0 + j], 0.f);
                float v = u16f((unsigned short)hv[j]) * sAsc[k0 + j] + sAsh[k0 + j] + SKIPC * v0;
                a[j] = (short)f2bu(fmaxf(v, 0.f));
            }
        }
        #pragma unroll
        for (int t = 0; t < MT; ++t) {
            int col = t * 16 + m;
            short8 b;
            if (col < MROWS) b = *(const short8*)(Wb + (size_t)col * 128 + k0);
            else             b = (short8){0,0,0,0,0,0,0,0};
            acc[t] = __builtin_amdgcn_mfma_f32_16x16x32_bf16(a, b, acc[t], 0, 0, 0);
        }
    }

    #pragma unroll
    for (int t = 0; t < MT; ++t) {
        int col = t * 16 + m;
        #pragma unroll
        for (int r = 0; r < 4; ++r) {
            int row = r0 + quad * 4 + r;
            if (row >= n) continue;
            if (col < MV) {
                Y[(size_t)row * MV + col] = f2bu(acc[t][r]);
            } else if (col < ALBASE + NH) {
                als[row * NH + (col - ALBASE)] = acc[t][r];
            } else if (col < ALBASE + 2 * NH) {
                ald[row * NH + (col - ALBASE - NH)] = acc[t][r];
            }
        }
    }
}

// FAT1 = binA (0..390) ∪ wcvt (391..551) ∪ wext_raw (552..560) — all read raw inputs only
__global__ __launch_bounds__(256) void fat1_k(const int* __restrict__ ei,
                                              int* __restrict__ bcnt,
                                              unsigned int* __restrict__ pairs,
                                              const void* __restrict__ W0,
                                              const void* __restrict__ W1,
                                              const void* __restrict__ W2,
                                              const void* __restrict__ as0, const void* __restrict__ ad0,
                                              const void* __restrict__ as1, const void* __restrict__ ad1,
                                              const void* __restrict__ as2, const void* __restrict__ ad2,
                                              unsigned short* __restrict__ Wb0,
                                              unsigned short* __restrict__ Wb1,
                                              unsigned short* __restrict__ Wb2,
                                              PrepJobs jobs,
                                              int* __restrict__ fflag) {
    if (blockIdx.x < BINA_BLKS) binA_body(blockIdx.x, ei, bcnt, pairs);
    else if (blockIdx.x < BINA_BLKS + 161)
        wcvt_body(blockIdx.x - BINA_BLKS, W0, W1, W2, Wb0, Wb1, Wb2, jobs, fflag);
    else
        wext_raw_body(blockIdx.x - BINA_BLKS - 161, W0, W1, W2,
                      as0, ad0, as1, ad1, as2, ad2, Wb0, Wb1, Wb2);
}

// FAT2B = binB (0..195) ∪ layer-0 GEMM (196..977)
__global__ __launch_bounds__(256) void fat2b_k(const int* __restrict__ bcnt,
                                               const unsigned int* __restrict__ pairs,
                                               int* __restrict__ row_ptr,
                                               int* __restrict__ ssrc,
                                               const void* __restrict__ X,
                                               const unsigned short* __restrict__ Wb,
                                               unsigned short* __restrict__ Y,
                                               float* __restrict__ als, float* __restrict__ ald,
                                               int n, const int* __restrict__ fflag) {
    if (blockIdx.x < NB) {
        binB_body(blockIdx.x, bcnt, pairs, row_ptr, ssrc);
    } else {
        int job = blockIdx.x - NB;
        if (fflag[0]) gemm_job<9, 128, 128, 4, 1>(job, X, nullptr, Wb, Y, als, ald, n,
                                                  nullptr, nullptr, nullptr, nullptr, nullptr, nullptr);
        else          gemm_job<9, 128, 128, 4, 0>(job, X, nullptr, Wb, Y, als, ald, n,
                                                  nullptr, nullptr, nullptr, nullptr, nullptr, nullptr);
    }
}

__global__ __launch_bounds__(256) void mfma_aff_k(const unsigned short* __restrict__ X,
                                                  const unsigned short* __restrict__ Wb,
                                                  unsigned short* __restrict__ Y,
                                                  float* __restrict__ als, float* __restrict__ ald,
                                                  int n,
                                                  const float* __restrict__ bn,
                                                  const float* __restrict__ g,
                                                  const float* __restrict__ be) {
    gemm_job<9, 128, 128, 4, 2>(blockIdx.x, X, nullptr, Wb, Y, als, ald, n,
                                bn, g, be, nullptr, nullptr, nullptr);
}

__global__ __launch_bounds__(256) void mfma_affskip_k(const unsigned short* __restrict__ X,
                                                      const unsigned short* __restrict__ Xprev,
                                                      const unsigned short* __restrict__ Wb,
                                                      unsigned short* __restrict__ Y,
                                                      float* __restrict__ als, float* __restrict__ ald,
                                                      int n,
                                                      const float* __restrict__ bnA,
                                                      const float* __restrict__ gA,
                                                      const float* __restrict__ beA,
                                                      const float* __restrict__ bnB,
                                                      const float* __restrict__ gB,
                                                      const float* __restrict__ beB) {
    gemm_job<3, 40, 40, 1, 3>(blockIdx.x, X, Xprev, Wb, Y, als, ald, n,
                              bnA, gA, beA, bnB, gB, beB);
}

// ---------- GAT aggregation: 3-deep pipelined gather, bf16 output ----------
template<int H, int C, int LPG, int CPL, bool FINAL>
__global__ __launch_bounds__(256) void agg4_k(const unsigned short* __restrict__ hbuf,
                                              const float* __restrict__ als,
                                              const float* __restrict__ ald,
                                              const float* __restrict__ bias,
                                              const int* __restrict__ row_ptr,
                                              const int* __restrict__ ssrc,
                                              void* __restrict__ out,
                                              const int* __restrict__ fflag, int n) {
    const int HC = H * C;
    const int G = 64 / LPG;
    const int NV = CPL / 8;
    int gw = (blockIdx.x * blockDim.x + threadIdx.x) >> 6;
    if (gw >= n) return;
    int lane = threadIdx.x & 63;
    int grp = lane / LPG;
    int sl  = lane % LPG;
    int c0 = sl * CPL;
    bool act = c0 < HC;
    int hl = act ? (c0 / C) : 0;
    int d = gw;
    int beg = row_ptr[d], end = row_ptr[d + 1];
    float adh = ald[d * H + hl];

    float denom = 0.f;
    float acc[CPL];
    #pragma unroll
    for (int j = 0; j < CPL; ++j) acc[j] = 0.f;

    int i0 = beg + grp;
    bool h0 = i0 < end;
    bool h1 = (i0 + G) < end;
    bool h2 = (i0 + 2 * G) < end;
    float al0 = 0.f, al1 = 0.f, al2 = 0.f;
    uint4 u0[NV], u1[NV], u2[NV];
    if (h0) {
        int s = ssrc[i0];
        al0 = als[s * H + hl];
        if (act) {
            const uint4* hp = (const uint4*)(hbuf + (size_t)s * HC + c0);
            #pragma unroll
            for (int v = 0; v < NV; ++v) u0[v] = hp[v];
        }
    }
    if (h1) {
        int s = ssrc[i0 + G];
        al1 = als[s * H + hl];
        if (act) {
            const uint4* hp = (const uint4*)(hbuf + (size_t)s * HC + c0);
            #pragma unroll
            for (int v = 0; v < NV; ++v) u1[v] = hp[v];
        }
    }
    if (h2) {
        int s = ssrc[i0 + 2 * G];
        al2 = als[s * H + hl];
        if (act) {
            const uint4* hp = (const uint4*)(hbuf + (size_t)s * HC + c0);
            #pragma unroll
            for (int v = 0; v < NV; ++v) u2[v] = hp[v];
        }
    }
    int inext = i0 + 3 * G;

    while (h0) {
        bool h3 = inext < end;
        float al3 = 0.f;
        uint4 u3[NV];
        if (h3) {
            int s = ssrc[inext];
            al3 = als[s * H + hl];
            if (act) {
                const uint4* hp = (const uint4*)(hbuf + (size_t)s * HC + c0);
                #pragma unroll
                for (int v = 0; v < NV; ++v) u3[v] = hp[v];
            }
        }
        float t = al0 + adh;
        t = t > 0.f ? t : NEG * t;
        float ex = __expf(t);
        denom += ex;
        if (act) {
            #pragma unroll
            for (int v = 0; v < NV; ++v) fma8(acc + v * 8, ex, u0[v]);
        }
        h0 = h1; al0 = al1;
        #pragma unroll
        for (int v = 0; v < NV; ++v) u0[v] = u1[v];
        h1 = h2; al1 = al2;
        #pragma unroll
        for (int v = 0; v < NV; ++v) u1[v] = u2[v];
        h2 = h3; al2 = al3;
        #pragma unroll
        for (int v = 0; v < NV; ++v) u2[v] = u3[v];
        inext += G;
    }

    #pragma unroll
    for (int off = LPG; off < 64; off <<= 1) {
        denom += __shfl_xor(denom, off, 64);
        #pragma unroll
        for (int j = 0; j < CPL; ++j) acc[j] += __shfl_xor(acc[j], off, 64);
    }

    if (grp == 0 && act) {
        float inv = 1.f / denom;
        float vals[CPL];
        #pragma unroll
        for (int j = 0; j < CPL; ++j) vals[j] = acc[j] * inv + bias[c0 + j];
        if (FINAL && !fflag[0]) {
            float* of = (float*)out + (size_t)d * HC + c0;
            #pragma unroll
            for (int j = 0; j < CPL; ++j) of[j] = vals[j];
        } else {
            unsigned short* ob = (unsigned short*)out + (size_t)d * HC + c0;
            #pragma unroll
            for (int v = 0; v < NV; ++v) {
                uint4 pk;
                pk.x = pk2(vals[v * 8 + 0], vals[v * 8 + 1]);
                pk.y = pk2(vals[v * 8 + 2], vals[v * 8 + 3]);
                pk.z = pk2(vals[v * 8 + 4], vals[v * 8 + 5]);
                pk.w = pk2(vals[v * 8 + 6], vals[v * 8 + 7]);
                *(uint4*)(ob + v * 8) = pk;
            }
        }
    }
}

// ---------- BatchNorm stats (bf16 input, vectorized short8 loads) ----------
__global__ __launch_bounds__(256) void bn_stats_k(const unsigned short* __restrict__ x,
                                                  float* __restrict__ sum,
                                                  float* __restrict__ sumsq, int n) {
    __shared__ float ss[128], sq[128];
    int t = threadIdx.x;
    int rt = t >> 4;            // 0..15 row within tile
    int c8 = (t & 15) * 8;      // channel base
    float s[8], q[8];
    #pragma unroll
    for (int j = 0; j < 8; ++j) { s[j] = 0.f; q[j] = 0.f; }
    for (int r = blockIdx.x * 16 + rt; r < n; r += gridDim.x * 16) {
        short8 v = *(const short8*)(x + (size_t)r * 128 + c8);
        #pragma unroll
        for (int j = 0; j < 8; ++j) {
            float f = u16f((unsigned short)v[j]);
            s[j] += f; q[j] += f * f;
        }
    }
    if (t < 128) { ss[t] = 0.f; sq[t] = 0.f; }
    __syncthreads();
    #pragma unroll
    for (int j = 0; j < 8; ++j) {
        atomicAdd(&ss[c8 + j], s[j]);
        atomicAdd(&sq[c8 + j], q[j]);
    }
    __syncthreads();
    if (t < 128) {
        atomicAdd(&sum[t], ss[t]);
        atomicAdd(&sumsq[t], sq[t]);
    }
}

// ---------- launch ----------
extern "C" void kernel_launch(void* const* d_in, const int* in_sizes, int n_in,
                              void* d_out, int out_size, void* d_ws, size_t ws_size,
                              hipStream_t stream) {
    const void* x   = d_in[0];
    const void* W0  = d_in[1];
    const void* as0 = d_in[2];
    const void* ad0 = d_in[3];
    const void* b0  = d_in[4];
    const void* g0  = d_in[5];
    const void* be0 = d_in[6];
    const void* W1  = d_in[7];
    const void* as1 = d_in[8];
    const void* ad1 = d_in[9];
    const void* b1  = d_in[10];
    const void* g1  = d_in[11];
    const void* be1 = d_in[12];
    const void* W2  = d_in[13];
    const void* as2 = d_in[14];
    const void* ad2 = d_in[15];
    const void* b2  = d_in[16];
    const int* ei = (const int*)d_in[17];

    char* w = (char*)d_ws;
    size_t off = 0;
    auto alloc = [&](size_t bytes) -> void* {
        void* p = w + off;
        off = (off + bytes + 255) & ~(size_t)255;
        return p;
    };
    unsigned short* hbf = (unsigned short*)alloc((size_t)N_NODES * 128 * 2);  // GEMM out
    unsigned short* hA0 = (unsigned short*)alloc((size_t)N_NODES * 128 * 2);  // agg out L0
    unsigned short* hA1 = (unsigned short*)alloc((size_t)N_NODES * 128 * 2);  // agg out L1
    float* als = (float*)alloc((size_t)N_NODES * 4 * 4);
    float* ald = (float*)alloc((size_t)N_NODES * 4 * 4);
    unsigned short* Wb0 = (unsigned short*)alloc((size_t)136 * 128 * 2);
    unsigned short* Wb1 = (unsigned short*)alloc((size_t)136 * 128 * 2);
    unsigned short* Wb2 = (unsigned short*)alloc((size_t)42 * 128 * 2);
    float* prm = (float*)alloc(2048 * 4);
    // contiguous zero-region: bcnt[NB] | bn0[256] | bn1[256]
    int* zreg = (int*)alloc((size_t)ZN * 4);
    int* bcnt = zreg;
    float* bn0 = (float*)(zreg + NB);
    float* bn1 = bn0 + 256;
    int* row_ptr = (int*)alloc((size_t)(N_NODES + 1) * 4);
    int* ssrc    = (int*)alloc((size_t)TOT_EDGES * 4);
    unsigned int* pairs = (unsigned int*)alloc((size_t)NB * BCAP * 4);
    int* fflag   = (int*)alloc(256);

    float* pAs0 = prm + 0,   * pAd0 = prm + 128,  * pB0 = prm + 256;
    float* pG0  = prm + 384, * pBe0 = prm + 512;
    float* pAs1 = prm + 640, * pAd1 = prm + 768,  * pB1 = prm + 896;
    float* pG1  = prm + 1024,* pBe1 = prm + 1152;
    float* pAs2 = prm + 1280,* pAd2 = prm + 1320, * pB2 = prm + 1360;

    if (off > ws_size) {
        zero_out_k<<<(out_size + 255) / 256, 256, 0, stream>>>((unsigned short*)d_out, out_size);
        return;
    }

    const int AB = (N_NODES * 64 + 255) / 256;

    PrepJobs jobs;
    const void* srcs[13] = { as0, ad0, b0, g0, be0, as1, ad1, b1, g1, be1, as2, ad2, b2 };
    float* dsts[13] = { pAs0, pAd0, pB0, pG0, pBe0, pAs1, pAd1, pB1, pG1, pBe1, pAs2, pAd2, pB2 };
    int ns[13] = { 128,128,128,128,128, 128,128,128,128,128, 40,40,40 };
    for (int i = 0; i < 13; ++i) { jobs.src[i] = srcs[i]; jobs.dst[i] = dsts[i]; jobs.n[i] = ns[i]; }

    // D1: zero bcnt + bn buffers
    hipMemsetAsync(zreg, 0, (size_t)ZN * 4, stream);
    // D2: CSR phase A ∪ weight/param convert ∪ extended-weight build (raw)
    fat1_k<<<BINA_BLKS + 161 + 9, 256, 0, stream>>>(ei, bcnt, pairs, W0, W1, W2,
                                                    as0, ad0, as1, ad1, as2, ad2,
                                                    Wb0, Wb1, Wb2, jobs, fflag);
    // D3: CSR phase B ∪ layer-0 GEMM
    fat2b_k<<<NB + GEMM_JOBS, 256, 0, stream>>>(bcnt, pairs, row_ptr, ssrc,
                                                x, Wb0, hbf, als, ald, N_NODES, fflag);
    // D4: layer-0 aggregation
    agg4_k<4, 32, 8, 16, false><<<AB, 256, 0, stream>>>(hbf, als, ald, pB0, row_ptr, ssrc, hA0, fflag, N_NODES);
    // D5: bn0 stats
    bn_stats_k<<<256, 256, 0, stream>>>(hA0, bn0, bn0 + 128, N_NODES);
    // D6: layer-1 GEMM (fuses bn0 + relu on A)
    mfma_aff_k<<<GEMM_JOBS, 256, 0, stream>>>(hA0, Wb1, hbf, als, ald, N_NODES, bn0, pG0, pBe0);
    // D7: layer-1 aggregation
    agg4_k<4, 32, 8, 16, false><<<AB, 256, 0, stream>>>(hbf, als, ald, pB1, row_ptr, ssrc, hA1, fflag, N_NODES);
    // D8: bn1 stats
    bn_stats_k<<<256, 256, 0, stream>>>(hA1, bn1, bn1 + 128, N_NODES);
    // D9: layer-2 GEMM (fuses bn1 + skip(bn0+relu) + relu on A)
    mfma_affskip_k<<<GEMM_JOBS, 256, 0, stream>>>(hA1, hA0, Wb2, hbf, als, ald, N_NODES,
                                                  bn1, pG1, pBe1, bn0, pG0, pBe0);
    // D10: layer-2 aggregation -> output
    agg4_k<1, 40, 8, 8, true><<<AB, 256, 0, stream>>>(hbf, als, ald, pB2, row_ptr, ssrc, d_out, fflag, N_NODES);
}

// Round 9
// 301.421 us; speedup vs baseline: 1.7172x; 1.0358x over previous
//
#include <hip/hip_runtime.h>
#include <hip/hip_bf16.h>
#include <stdint.h>

#define N_NODES 50000
#define N_EDGES 800000
#define TOT_EDGES (N_EDGES + N_NODES)
#define DIM 128
#define NEG 0.2f
#define BN_EPS 1e-5f
#define SKIPC 0.5f
#define NB 196          // buckets of 256 dst nodes
#define BCAP 6144       // per-bucket capacity (mean 4082, +31 sigma)
#define EPB 2048        // edges per binA block
#define BINA_BLKS ((N_EDGES + EPB - 1) / EPB)   // 391
#define GEMM_JOBS ((N_NODES + 127) >> 7)        // 391 (128 rows per block, 32 per wave)
#define ZN (NB + 512)

typedef __attribute__((ext_vector_type(8))) short short8;
typedef __attribute__((ext_vector_type(4))) float f32x4;

// ---------- helpers ----------
__device__ inline float bf2f(__hip_bfloat16 v) { return __bfloat162float(v); }
__device__ inline float u16f(unsigned short u) { return __uint_as_float(((unsigned int)u) << 16); }
__device__ inline unsigned short f2bu(float f) {
    __hip_bfloat16 b = __float2bfloat16(f);
    return *(unsigned short*)&b;
}
__device__ inline void fma8(float* acc, float ex, uint4 u) {
    acc[0] += ex * u16f((unsigned short)(u.x & 0xFFFFu));
    acc[1] += ex * u16f((unsigned short)(u.x >> 16));
    acc[2] += ex * u16f((unsigned short)(u.y & 0xFFFFu));
    acc[3] += ex * u16f((unsigned short)(u.y >> 16));
    acc[4] += ex * u16f((unsigned short)(u.z & 0xFFFFu));
    acc[5] += ex * u16f((unsigned short)(u.z >> 16));
    acc[6] += ex * u16f((unsigned short)(u.w & 0xFFFFu));
    acc[7] += ex * u16f((unsigned short)(u.w >> 16));
}
__device__ inline unsigned int pk2(float a, float b) {
    return (unsigned int)f2bu(a) | ((unsigned int)f2bu(b) << 16);
}

// ---------- fallback (ws too small) ----------
__global__ void zero_out_k(unsigned short* out, int n) {
    int g = blockIdx.x * 256 + threadIdx.x;
    if (g < n) out[g] = 0;
}

// ---------- CSR build phase A (bucketed scatter; self-detects int64/int32) ----------
__device__ inline void binA_body(int bid, const int* __restrict__ ei,
                                 int* __restrict__ bcnt,
                                 unsigned int* __restrict__ pairs) {
    __shared__ int cnt[NB], base[NB], cur[NB];
    __shared__ int sf;
    int t = threadIdx.x;
    if (t == 0) sf = 0;
    for (int i = t; i < NB; i += 256) cnt[i] = 0;
    __syncthreads();
    if (t < 16 && ei[2 * t + 1] != 0) atomicOr(&sf, 1);
    __syncthreads();
    int f = (sf == 0);   // 1 => int64
    int b0 = bid * EPB;
    unsigned int pk[8];
    int bk[8];
    #pragma unroll
    for (int j = 0; j < 8; ++j) bk[j] = -1;

    auto handle = [&](int slot, int s, int d) {
        if ((unsigned)d < N_NODES && (unsigned)s < N_NODES) {
            bk[slot] = d >> 8;
            pk[slot] = (unsigned int)s | ((unsigned int)(d & 255) << 16);
            atomicAdd(&cnt[bk[slot]], 1);
        }
    };

    if (f) {
        #pragma unroll
        for (int j = 0; j < 4; ++j) {
            int i0 = b0 + j * 512 + 2 * t;
            if (i0 < N_EDGES) {
                int4 sv = *(const int4*)(ei + 2 * (size_t)i0);
                int4 dv = *(const int4*)(ei + 2 * ((size_t)N_EDGES + i0));
                handle(2 * j, sv.x, dv.x);
                if (i0 + 1 < N_EDGES) handle(2 * j + 1, sv.z, dv.z);
            }
        }
    } else {
        #pragma unroll
        for (int j = 0; j < 8; ++j) {
            int g = b0 + j * 256 + t;
            if (g < N_EDGES) handle(j, ei[g], ei[N_EDGES + g]);
        }
    }
    __syncthreads();
    if (t < NB) {
        int c = cnt[t];
        base[t] = c ? atomicAdd(&bcnt[t], c) : 0;
        cur[t] = 0;
    }
    __syncthreads();
    #pragma unroll
    for (int j = 0; j < 8; ++j) {
        if (bk[j] >= 0) {
            int off = base[bk[j]] + atomicAdd(&cur[bk[j]], 1);
            if (off < BCAP) pairs[(size_t)bk[j] * BCAP + off] = pk[j];
        }
    }
}

// ---------- weight/param convert + dtype detect ----------
struct PrepJobs { const void* src[13]; float* dst[13]; int n[13]; };
__device__ inline void wcvt_body(int bid,
                                 const void* __restrict__ W0,
                                 const void* __restrict__ W1,
                                 const void* __restrict__ W2,
                                 unsigned short* __restrict__ Wb0,
                                 unsigned short* __restrict__ Wb1,
                                 unsigned short* __restrict__ Wb2,
                                 const PrepJobs& jobs,
                                 int* __restrict__ fflag) {
    __shared__ int cs;
    int t = threadIdx.x;
    if (t == 0) cs = 0;
    __syncthreads();
    {
        unsigned int w = ((const unsigned int*)W0)[t];
        float v0 = u16f((unsigned short)(w & 0xFFFFu));
        float a = fabsf(v0);
        int sane = (a < 2.0f && (a > 1e-20f || v0 == 0.0f)) ? 1 : 0;
        atomicAdd(&cs, sane);
    }
    __syncthreads();
    int f = (cs >= 128) ? 1 : 0;
    if (bid == 0 && t == 0) fflag[0] = f;
    if (bid < 148) {
        int g = bid * 256 + t;
        const void* W; unsigned short* Wb; int idx;
        if (g < 16384)        { W = W0; Wb = Wb0; idx = g; }
        else if (g < 32768)   { W = W1; Wb = Wb1; idx = g - 16384; }
        else if (g < 37888)   { W = W2; Wb = Wb2; idx = g - 32768; }
        else return;
        if (f) Wb[idx] = ((const unsigned short*)W)[idx];
        else   Wb[idx] = f2bu(((const float*)W)[idx]);
    } else {
        int j = bid - 148;
        int n = jobs.n[j];
        const void* s = jobs.src[j];
        float* d = jobs.dst[j];
        for (int i = t; i < n; i += 256)
            d[i] = f ? bf2f(((const __hip_bfloat16*)s)[i]) : ((const float*)s)[i];
    }
}

// ---------- extended-weight build from RAW inputs (independent of wcvt) ----------
__device__ inline void wext_raw_body(int bid,
                                     const void* __restrict__ W0,
                                     const void* __restrict__ W1,
                                     const void* __restrict__ W2,
                                     const void* __restrict__ as0, const void* __restrict__ ad0,
                                     const void* __restrict__ as1, const void* __restrict__ ad1,
                                     const void* __restrict__ as2, const void* __restrict__ ad2,
                                     unsigned short* __restrict__ Wb0,
                                     unsigned short* __restrict__ Wb1,
                                     unsigned short* __restrict__ Wb2) {
    __shared__ int cs;
    int t = threadIdx.x;
    if (t == 0) cs = 0;
    __syncthreads();
    {
        unsigned int w = ((const unsigned int*)W0)[t];
        float v0 = u16f((unsigned short)(w & 0xFFFFu));
        float a = fabsf(v0);
        int sane = (a < 2.0f && (a > 1e-20f || v0 == 0.0f)) ? 1 : 0;
        atomicAdd(&cs, sane);
    }
    __syncthreads();
    int f = (cs >= 128) ? 1 : 0;
    auto rd = [&](const void* p, int idx) -> float {
        return f ? u16f(((const unsigned short*)p)[idx]) : ((const float*)p)[idx];
    };
    int g = bid * 256 + t;
    if (g < 2048) {
        int layer = g >> 10;
        int gi = g & 1023;
        int rowq = gi >> 7;
        int k = gi & 127;
        int hh = rowq & 3, dir = rowq >> 2;
        const void* W = layer ? W1 : W0;
        const void* p = layer ? (dir ? ad1 : as1) : (dir ? ad0 : as0);
        unsigned short* Wb = layer ? Wb1 : Wb0;
        float v = 0.f;
        #pragma unroll
        for (int c = 0; c < 32; ++c)
            v += rd(p, hh * 32 + c) * rd(W, (hh * 32 + c) * 128 + k);
        Wb[(size_t)(128 + dir * 4 + hh) * 128 + k] = f2bu(v);
    } else if (g < 2304) {
        int gi = g - 2048;
        int dir = gi >> 7;
        int k = gi & 127;
        const void* p = dir ? ad2 : as2;
        float v = 0.f;
        #pragma unroll
        for (int c = 0; c < 40; ++c)
            v += rd(p, c) * rd(W2, c * 128 + k);
        Wb2[(size_t)(40 + dir) * 128 + k] = f2bu(v);
    }
}

// ---------- CSR build phase B ----------
__device__ inline void binB_body(int b, const int* __restrict__ bcnt,
                                 const unsigned int* __restrict__ pairs,
                                 int* __restrict__ row_ptr,
                                 int* __restrict__ ssrc) {
    __shared__ int cntL[256], scanL[256], curL[256];
    __shared__ int sred[256];
    int t = threadIdx.x;
    int n0 = b * 256;
    int nn = min(256, N_NODES - n0);
    int cnt_b = min(bcnt[b], BCAP);
    int contrib = 0;
    if (t < b) contrib = min(bcnt[t], BCAP) + min(256, N_NODES - t * 256);
    sred[t] = contrib;
    __syncthreads();
    #pragma unroll
    for (int off = 128; off > 0; off >>= 1) {
        if (t < off) sred[t] += sred[t + off];
        __syncthreads();
    }
    int gbase = sred[0];
    if (b == NB - 1 && t == 0) row_ptr[N_NODES] = gbase + cnt_b + nn;

    const unsigned int* P = pairs + (size_t)b * BCAP;
    cntL[t] = (t < nn) ? 1 : 0;
    __syncthreads();
    for (int i = t; i < cnt_b; i += 256)
        atomicAdd(&cntL[P[i] >> 16], 1);
    __syncthreads();
    int v = cntL[t];
    scanL[t] = v;
    __syncthreads();
    for (int off = 1; off < 256; off <<= 1) {
        int x = (t >= off) ? scanL[t - off] : 0;
        __syncthreads();
        scanL[t] += x;
        __syncthreads();
    }
    int excl = scanL[t] - v;
    if (t < nn) row_ptr[n0 + t] = gbase + excl;
    curL[t] = excl;
    __syncthreads();
    if (t < nn) {
        int pos = atomicAdd(&curL[t], 1);
        ssrc[gbase + pos] = n0 + t;
    }
    for (int i = t; i < cnt_b; i += 256) {
        unsigned int p = P[i];
        int pos = atomicAdd(&curL[p >> 16], 1);
        ssrc[gbase + pos] = (int)(p & 0xFFFFu);
    }
}

// ---------- GEMM job body: 32 rows per wave, B fragments reused across both 16-row tiles ----------
// AMODE 0: external X f32   AMODE 1: external X bf16
// AMODE 2: A = relu(X*scA+shA)   AMODE 3: A = relu(X*scA+shA + 0.5*relu(Xp*scB+shB))
template<int AMODE>
__device__ inline short8 load_a_frag(const void* __restrict__ X,
                                     const unsigned short* __restrict__ Xprev,
                                     int arow, int k0,
                                     const float* sAsc, const float* sAsh,
                                     const float* sBsc, const float* sBsh) {
    short8 a;
    if (AMODE == 0) {
        const float* xp = (const float*)X + (size_t)arow * 128 + k0;
        float4 x0 = *(const float4*)xp;
        float4 x1 = *(const float4*)(xp + 4);
        a[0] = (short)f2bu(x0.x); a[1] = (short)f2bu(x0.y);
        a[2] = (short)f2bu(x0.z); a[3] = (short)f2bu(x0.w);
        a[4] = (short)f2bu(x1.x); a[5] = (short)f2bu(x1.y);
        a[6] = (short)f2bu(x1.z); a[7] = (short)f2bu(x1.w);
    } else if (AMODE == 1) {
        a = *(const short8*)((const unsigned short*)X + (size_t)arow * 128 + k0);
    } else if (AMODE == 2) {
        short8 hv = *(const short8*)((const unsigned short*)X + (size_t)arow * 128 + k0);
        #pragma unroll
        for (int j = 0; j < 8; ++j) {
            float v = u16f((unsigned short)hv[j]) * sAsc[k0 + j] + sAsh[k0 + j];
            a[j] = (short)f2bu(fmaxf(v, 0.f));
        }
    } else {
        short8 hv = *(const short8*)((const unsigned short*)X + (size_t)arow * 128 + k0);
        short8 pv = *(const short8*)(Xprev + (size_t)arow * 128 + k0);
        #pragma unroll
        for (int j = 0; j < 8; ++j) {
            float v0 = fmaxf(u16f((unsigned short)pv[j]) * sBsc[k0 + j] + sBsh[k0 + j], 0.f);
            float v = u16f((unsigned short)hv[j]) * sAsc[k0 + j] + sAsh[k0 + j] + SKIPC * v0;
            a[j] = (short)f2bu(fmaxf(v, 0.f));
        }
    }
    return a;
}

template<int MT, int MV, int ALBASE, int NH, int AMODE>
__device__ inline void gemm_job(int job,
                                const void* __restrict__ X,
                                const unsigned short* __restrict__ Xprev,
                                const unsigned short* __restrict__ Wb,
                                unsigned short* __restrict__ Y,
                                float* __restrict__ als, float* __restrict__ ald, int n,
                                const float* __restrict__ bnA, const float* __restrict__ gA,
                                const float* __restrict__ beA,
                                const float* __restrict__ bnB, const float* __restrict__ gB,
                                const float* __restrict__ beB) {
    const int MROWS = ALBASE + 2 * NH;
    __shared__ float sAsc[128], sAsh[128], sBsc[128], sBsh[128];
    if (AMODE >= 2) {
        int t = threadIdx.x;
        const float invN = 1.f / (float)N_NODES;
        if (t < 128) {
            float mean = bnA[t] * invN;
            float var = fmaxf(bnA[128 + t] * invN - mean * mean, 0.f);
            float s = rsqrtf(var + BN_EPS) * gA[t];
            sAsc[t] = s;
            sAsh[t] = beA[t] - mean * s;
        } else if (AMODE == 3) {
            int c = t - 128;
            float mean = bnB[c] * invN;
            float var = fmaxf(bnB[128 + c] * invN - mean * mean, 0.f);
            float s = rsqrtf(var + BN_EPS) * gB[c];
            sBsc[c] = s;
            sBsh[c] = beB[c] - mean * s;
        }
        __syncthreads();
    }
    int lane = threadIdx.x & 63;
    int m = lane & 15, quad = lane >> 4;
    int wl = threadIdx.x >> 6;
    int r0 = (job << 7) + (wl << 5);   // 32 rows per wave
    if (r0 >= n) return;
    f32x4 acc0[MT], acc1[MT];
    #pragma unroll
    for (int t = 0; t < MT; ++t) {
        acc0[t] = (f32x4){0.f, 0.f, 0.f, 0.f};
        acc1[t] = (f32x4){0.f, 0.f, 0.f, 0.f};
    }
    int arow0 = min(r0 + m, n - 1);
    int arow1 = min(r0 + 16 + m, n - 1);
    bool tile1 = (r0 + 16) < n;

    #pragma unroll
    for (int kc = 0; kc < 4; ++kc) {
        int k0 = kc * 32 + quad * 8;
        short8 a0 = load_a_frag<AMODE>(X, Xprev, arow0, k0, sAsc, sAsh, sBsc, sBsh);
        short8 a1 = load_a_frag<AMODE>(X, Xprev, arow1, k0, sAsc, sAsh, sBsc, sBsh);
        #pragma unroll
        for (int t = 0; t < MT; ++t) {
            int col = t * 16 + m;
            short8 b;
            if (col < MROWS) b = *(const short8*)(Wb + (size_t)col * 128 + k0);
            else             b = (short8){0,0,0,0,0,0,0,0};
            acc0[t] = __builtin_amdgcn_mfma_f32_16x16x32_bf16(a0, b, acc0[t], 0, 0, 0);
            acc1[t] = __builtin_amdgcn_mfma_f32_16x16x32_bf16(a1, b, acc1[t], 0, 0, 0);
        }
    }

    #pragma unroll
    for (int t = 0; t < MT; ++t) {
        int col = t * 16 + m;
        #pragma unroll
        for (int r = 0; r < 4; ++r) {
            int row = r0 + quad * 4 + r;
            if (row < n) {
                if (col < MV) {
                    Y[(size_t)row * MV + col] = f2bu(acc0[t][r]);
                } else if (col < ALBASE + NH) {
                    als[row * NH + (col - ALBASE)] = acc0[t][r];
                } else if (col < ALBASE + 2 * NH) {
                    ald[row * NH + (col - ALBASE - NH)] = acc0[t][r];
                }
            }
            if (tile1) {
                int row1 = r0 + 16 + quad * 4 + r;
                if (row1 < n) {
                    if (col < MV) {
                        Y[(size_t)row1 * MV + col] = f2bu(acc1[t][r]);
                    } else if (col < ALBASE + NH) {
                        als[row1 * NH + (col - ALBASE)] = acc1[t][r];
                    } else if (col < ALBASE + 2 * NH) {
                        ald[row1 * NH + (col - ALBASE - NH)] = acc1[t][r];
                    }
                }
            }
        }
    }
}

// FAT1 = binA (0..390) ∪ wcvt (391..551) ∪ wext_raw (552..560) — all read raw inputs only
__global__ __launch_bounds__(256) void fat1_k(const int* __restrict__ ei,
                                              int* __restrict__ bcnt,
                                              unsigned int* __restrict__ pairs,
                                              const void* __restrict__ W0,
                                              const void* __restrict__ W1,
                                              const void* __restrict__ W2,
                                              const void* __restrict__ as0, const void* __restrict__ ad0,
                                              const void* __restrict__ as1, const void* __restrict__ ad1,
                                              const void* __restrict__ as2, const void* __restrict__ ad2,
                                              unsigned short* __restrict__ Wb0,
                                              unsigned short* __restrict__ Wb1,
                                              unsigned short* __restrict__ Wb2,
                                              PrepJobs jobs,
                                              int* __restrict__ fflag) {
    if (blockIdx.x < BINA_BLKS) binA_body(blockIdx.x, ei, bcnt, pairs);
    else if (blockIdx.x < BINA_BLKS + 161)
        wcvt_body(blockIdx.x - BINA_BLKS, W0, W1, W2, Wb0, Wb1, Wb2, jobs, fflag);
    else
        wext_raw_body(blockIdx.x - BINA_BLKS - 161, W0, W1, W2,
                      as0, ad0, as1, ad1, as2, ad2, Wb0, Wb1, Wb2);
}

// FAT2B = binB (0..195) ∪ layer-0 GEMM (196..586)
__global__ __launch_bounds__(256) void fat2b_k(const int* __restrict__ bcnt,
                                               const unsigned int* __restrict__ pairs,
                                               int* __restrict__ row_ptr,
                                               int* __restrict__ ssrc,
                                               const void* __restrict__ X,
                                               const unsigned short* __restrict__ Wb,
                                               unsigned short* __restrict__ Y,
                                               float* __restrict__ als, float* __restrict__ ald,
                                               int n, const int* __restrict__ fflag) {
    if (blockIdx.x < NB) {
        binB_body(blockIdx.x, bcnt, pairs, row_ptr, ssrc);
    } else {
        int job = blockIdx.x - NB;
        if (fflag[0]) gemm_job<9, 128, 128, 4, 1>(job, X, nullptr, Wb, Y, als, ald, n,
                                                  nullptr, nullptr, nullptr, nullptr, nullptr, nullptr);
        else          gemm_job<9, 128, 128, 4, 0>(job, X, nullptr, Wb, Y, als, ald, n,
                                                  nullptr, nullptr, nullptr, nullptr, nullptr, nullptr);
    }
}

__global__ __launch_bounds__(256) void mfma_aff_k(const unsigned short* __restrict__ X,
                                                  const unsigned short* __restrict__ Wb,
                                                  unsigned short* __restrict__ Y,
                                                  float* __restrict__ als, float* __restrict__ ald,
                                                  int n,
                                                  const float* __restrict__ bn,
                                                  const float* __restrict__ g,
                                                  const float* __restrict__ be) {
    gemm_job<9, 128, 128, 4, 2>(blockIdx.x, X, nullptr, Wb, Y, als, ald, n,
                                bn, g, be, nullptr, nullptr, nullptr);
}

__global__ __launch_bounds__(256) void mfma_affskip_k(const unsigned short* __restrict__ X,
                                                      const unsigned short* __restrict__ Xprev,
                                                      const unsigned short* __restrict__ Wb,
                                                      unsigned short* __restrict__ Y,
                                                      float* __restrict__ als, float* __restrict__ ald,
                                                      int n,
                                                      const float* __restrict__ bnA,
                                                      const float* __restrict__ gA,
                                                      const float* __restrict__ beA,
                                                      const float* __restrict__ bnB,
                                                      const float* __restrict__ gB,
                                                      const float* __restrict__ beB) {
    gemm_job<3, 40, 40, 1, 3>(blockIdx.x, X, Xprev, Wb, Y, als, ald, n,
                              bnA, gA, beA, bnB, gB, beB);
}

// ---------- GAT aggregation: 3-deep pipelined gather, bf16 output ----------
template<int H, int C, int LPG, int CPL, bool FINAL>
__global__ __launch_bounds__(256) void agg4_k(const unsigned short* __restrict__ hbuf,
                                              const float* __restrict__ als,
                                              const float* __restrict__ ald,
                                              const float* __restrict__ bias,
                                              const int* __restrict__ row_ptr,
                                              const int* __restrict__ ssrc,
                                              void* __restrict__ out,
                                              const int* __restrict__ fflag, int n) {
    const int HC = H * C;
    const int G = 64 / LPG;
    const int NV = CPL / 8;
    int gw = (blockIdx.x * blockDim.x + threadIdx.x) >> 6;
    if (gw >= n) return;
    int lane = threadIdx.x & 63;
    int grp = lane / LPG;
    int sl  = lane % LPG;
    int c0 = sl * CPL;
    bool act = c0 < HC;
    int hl = act ? (c0 / C) : 0;
    int d = gw;
    int beg = row_ptr[d], end = row_ptr[d + 1];
    float adh = ald[d * H + hl];

    float denom = 0.f;
    float acc[CPL];
    #pragma unroll
    for (int j = 0; j < CPL; ++j) acc[j] = 0.f;

    int i0 = beg + grp;
    bool h0 = i0 < end;
    bool h1 = (i0 + G) < end;
    bool h2 = (i0 + 2 * G) < end;
    float al0 = 0.f, al1 = 0.f, al2 = 0.f;
    uint4 u0[NV], u1[NV], u2[NV];
    if (h0) {
        int s = ssrc[i0];
        al0 = als[s * H + hl];
        if (act) {
            const uint4* hp = (const uint4*)(hbuf + (size_t)s * HC + c0);
            #pragma unroll
            for (int v = 0; v < NV; ++v) u0[v] = hp[v];
        }
    }
    if (h1) {
        int s = ssrc[i0 + G];
        al1 = als[s * H + hl];
        if (act) {
            const uint4* hp = (const uint4*)(hbuf + (size_t)s * HC + c0);
            #pragma unroll
            for (int v = 0; v < NV; ++v) u1[v] = hp[v];
        }
    }
    if (h2) {
        int s = ssrc[i0 + 2 * G];
        al2 = als[s * H + hl];
        if (act) {
            const uint4* hp = (const uint4*)(hbuf + (size_t)s * HC + c0);
            #pragma unroll
            for (int v = 0; v < NV; ++v) u2[v] = hp[v];
        }
    }
    int inext = i0 + 3 * G;

    while (h0) {
        bool h3 = inext < end;
        float al3 = 0.f;
        uint4 u3[NV];
        if (h3) {
            int s = ssrc[inext];
            al3 = als[s * H + hl];
            if (act) {
                const uint4* hp = (const uint4*)(hbuf + (size_t)s * HC + c0);
                #pragma unroll
                for (int v = 0; v < NV; ++v) u3[v] = hp[v];
            }
        }
        float t = al0 + adh;
        t = t > 0.f ? t : NEG * t;
        float ex = __expf(t);
        denom += ex;
        if (act) {
            #pragma unroll
            for (int v = 0; v < NV; ++v) fma8(acc + v * 8, ex, u0[v]);
        }
        h0 = h1; al0 = al1;
        #pragma unroll
        for (int v = 0; v < NV; ++v) u0[v] = u1[v];
        h1 = h2; al1 = al2;
        #pragma unroll
        for (int v = 0; v < NV; ++v) u1[v] = u2[v];
        h2 = h3; al2 = al3;
        #pragma unroll
        for (int v = 0; v < NV; ++v) u2[v] = u3[v];
        inext += G;
    }

    #pragma unroll
    for (int off = LPG; off < 64; off <<= 1) {
        denom += __shfl_xor(denom, off, 64);
        #pragma unroll
        for (int j = 0; j < CPL; ++j) acc[j] += __shfl_xor(acc[j], off, 64);
    }

    if (grp == 0 && act) {
        float inv = 1.f / denom;
        float vals[CPL];
        #pragma unroll
        for (int j = 0; j < CPL; ++j) vals[j] = acc[j] * inv + bias[c0 + j];
        if (FINAL && !fflag[0]) {
            float* of = (float*)out + (size_t)d * HC + c0;
            #pragma unroll
            for (int j = 0; j < CPL; ++j) of[j] = vals[j];
        } else {
            unsigned short* ob = (unsigned short*)out + (size_t)d * HC + c0;
            #pragma unroll
            for (int v = 0; v < NV; ++v) {
                uint4 pk;
                pk.x = pk2(vals[v * 8 + 0], vals[v * 8 + 1]);
                pk.y = pk2(vals[v * 8 + 2], vals[v * 8 + 3]);
                pk.z = pk2(vals[v * 8 + 4], vals[v * 8 + 5]);
                pk.w = pk2(vals[v * 8 + 6], vals[v * 8 + 7]);
                *(uint4*)(ob + v * 8) = pk;
            }
        }
    }
}

// ---------- BatchNorm stats (bf16 input, vectorized short8 loads) ----------
__global__ __launch_bounds__(256) void bn_stats_k(const unsigned short* __restrict__ x,
                                                  float* __restrict__ sum,
                                                  float* __restrict__ sumsq, int n) {
    __shared__ float ss[128], sq[128];
    int t = threadIdx.x;
    int rt = t >> 4;            // 0..15 row within tile
    int c8 = (t & 15) * 8;      // channel base
    float s[8], q[8];
    #pragma unroll
    for (int j = 0; j < 8; ++j) { s[j] = 0.f; q[j] = 0.f; }
    for (int r = blockIdx.x * 16 + rt; r < n; r += gridDim.x * 16) {
        short8 v = *(const short8*)(x + (size_t)r * 128 + c8);
        #pragma unroll
        for (int j = 0; j < 8; ++j) {
            float f = u16f((unsigned short)v[j]);
            s[j] += f; q[j] += f * f;
        }
    }
    if (t < 128) { ss[t] = 0.f; sq[t] = 0.f; }
    __syncthreads();
    #pragma unroll
    for (int j = 0; j < 8; ++j) {
        atomicAdd(&ss[c8 + j], s[j]);
        atomicAdd(&sq[c8 + j], q[j]);
    }
    __syncthreads();
    if (t < 128) {
        atomicAdd(&sum[t], ss[t]);
        atomicAdd(&sumsq[t], sq[t]);
    }
}

// ---------- launch ----------
extern "C" void kernel_launch(void* const* d_in, const int* in_sizes, int n_in,
                              void* d_out, int out_size, void* d_ws, size_t ws_size,
                              hipStream_t stream) {
    const void* x   = d_in[0];
    const void* W0  = d_in[1];
    const void* as0 = d_in[2];
    const void* ad0 = d_in[3];
    const void* b0  = d_in[4];
    const void* g0  = d_in[5];
    const void* be0 = d_in[6];
    const void* W1  = d_in[7];
    const void* as1 = d_in[8];
    const void* ad1 = d_in[9];
    const void* b1  = d_in[10];
    const void* g1  = d_in[11];
    const void* be1 = d_in[12];
    const void* W2  = d_in[13];
    const void* as2 = d_in[14];
    const void* ad2 = d_in[15];
    const void* b2  = d_in[16];
    const int* ei = (const int*)d_in[17];

    char* w = (char*)d_ws;
    size_t off = 0;
    auto alloc = [&](size_t bytes) -> void* {
        void* p = w + off;
        off = (off + bytes + 255) & ~(size_t)255;
        return p;
    };
    unsigned short* hbf = (unsigned short*)alloc((size_t)N_NODES * 128 * 2);  // GEMM out
    unsigned short* hA0 = (unsigned short*)alloc((size_t)N_NODES * 128 * 2);  // agg out L0
    unsigned short* hA1 = (unsigned short*)alloc((size_t)N_NODES * 128 * 2);  // agg out L1
    float* als = (float*)alloc((size_t)N_NODES * 4 * 4);
    float* ald = (float*)alloc((size_t)N_NODES * 4 * 4);
    unsigned short* Wb0 = (unsigned short*)alloc((size_t)136 * 128 * 2);
    unsigned short* Wb1 = (unsigned short*)alloc((size_t)136 * 128 * 2);
    unsigned short* Wb2 = (unsigned short*)alloc((size_t)42 * 128 * 2);
    float* prm = (float*)alloc(2048 * 4);
    // contiguous zero-region: bcnt[NB] | bn0[256] | bn1[256]
    int* zreg = (int*)alloc((size_t)ZN * 4);
    int* bcnt = zreg;
    float* bn0 = (float*)(zreg + NB);
    float* bn1 = bn0 + 256;
    int* row_ptr = (int*)alloc((size_t)(N_NODES + 1) * 4);
    int* ssrc    = (int*)alloc((size_t)TOT_EDGES * 4);
    unsigned int* pairs = (unsigned int*)alloc((size_t)NB * BCAP * 4);
    int* fflag   = (int*)alloc(256);

    float* pAs0 = prm + 0,   * pAd0 = prm + 128,  * pB0 = prm + 256;
    float* pG0  = prm + 384, * pBe0 = prm + 512;
    float* pAs1 = prm + 640, * pAd1 = prm + 768,  * pB1 = prm + 896;
    float* pG1  = prm + 1024,* pBe1 = prm + 1152;
    float* pAs2 = prm + 1280,* pAd2 = prm + 1320, * pB2 = prm + 1360;

    if (off > ws_size) {
        zero_out_k<<<(out_size + 255) / 256, 256, 0, stream>>>((unsigned short*)d_out, out_size);
        return;
    }

    const int AB = (N_NODES * 64 + 255) / 256;

    PrepJobs jobs;
    const void* srcs[13] = { as0, ad0, b0, g0, be0, as1, ad1, b1, g1, be1, as2, ad2, b2 };
    float* dsts[13] = { pAs0, pAd0, pB0, pG0, pBe0, pAs1, pAd1, pB1, pG1, pBe1, pAs2, pAd2, pB2 };
    int ns[13] = { 128,128,128,128,128, 128,128,128,128,128, 40,40,40 };
    for (int i = 0; i < 13; ++i) { jobs.src[i] = srcs[i]; jobs.dst[i] = dsts[i]; jobs.n[i] = ns[i]; }

    // D1: zero bcnt + bn buffers
    hipMemsetAsync(zreg, 0, (size_t)ZN * 4, stream);
    // D2: CSR phase A ∪ weight/param convert ∪ extended-weight build (raw)
    fat1_k<<<BINA_BLKS + 161 + 9, 256, 0, stream>>>(ei, bcnt, pairs, W0, W1, W2,
                                                    as0, ad0, as1, ad1, as2, ad2,
                                                    Wb0, Wb1, Wb2, jobs, fflag);
    // D3: CSR phase B ∪ layer-0 GEMM
    fat2b_k<<<NB + GEMM_JOBS, 256, 0, stream>>>(bcnt, pairs, row_ptr, ssrc,
                                                x, Wb0, hbf, als, ald, N_NODES, fflag);
    // D4: layer-0 aggregation
    agg4_k<4, 32, 8, 16, false><<<AB, 256, 0, stream>>>(hbf, als, ald, pB0, row_ptr, ssrc, hA0, fflag, N_NODES);
    // D5: bn0 stats
    bn_stats_k<<<256, 256, 0, stream>>>(hA0, bn0, bn0 + 128, N_NODES);
    // D6: layer-1 GEMM (fuses bn0 + relu on A)
    mfma_aff_k<<<GEMM_JOBS, 256, 0, stream>>>(hA0, Wb1, hbf, als, ald, N_NODES, bn0, pG0, pBe0);
    // D7: layer-1 aggregation
    agg4_k<4, 32, 8, 16, false><<<AB, 256, 0, stream>>>(hbf, als, ald, pB1, row_ptr, ssrc, hA1, fflag, N_NODES);
    // D8: bn1 stats
    bn_stats_k<<<256, 256, 0, stream>>>(hA1, bn1, bn1 + 128, N_NODES);
    // D9: layer-2 GEMM (fuses bn1 + skip(bn0+relu) + relu on A)
    mfma_affskip_k<<<GEMM_JOBS, 256, 0, stream>>>(hA1, hA0, Wb2, hbf, als, ald, N_NODES,
                                                  bn1, pG1, pBe1, bn0, pG0, pBe0);
    // D10: layer-2 aggregation -> output
    agg4_k<1, 40, 8, 8, true><<<AB, 256, 0, stream>>>(hbf, als, ald, pB2, row_ptr, ssrc, d_out, fflag, N_NODES);
}